// Round 8
// baseline (884.342 us; speedup 1.0000x reference)
//
#include <hip/hip_runtime.h>
#include <math.h>
#include <string.h>

// V2VNetFusion on MI355X, round 12: B-operand direct-from-global.
// r11 post-mortem: single-buffered staging issued DMAs immediately
// before the barrier that drains them (fully exposed HBM latency each
// kb), and CF=2 weights are 18432B (not 9216) -> LDS 40448, ~3 blocks.
// Key insight: in the pixel-interleaved [half][pix][32ch] layout a
// wave's MFMA B-frag read is PERFECTLY coalesced from global: lane
// (q,n16) reads pixel n16 bytes q*16 -> wave touches 16px x 64B = 1KB
// contiguous. Tile working set (~22KB/kb) is L1/L2-resident with 6.8x
// reuse across kx/ky/q. So: NO input LDS, no staging, no halo, no
// swizzle. LDS = double-buffered weights only (2x18432B -> 4 blocks/CU,
// 16 waves), 1 barrier/kb, weight DMA flies over a full compute phase.
// OOB handling: uniform row-skip (frag=0); per-lane col masking only in
// the two uniform edge cases (x0p==0 kx==0 p-even; x0p==320 kx==2 p-odd).
#define HH 200
#define WW 352
#define HWSZ (HH*WW)          // 70400
#define CHW (64L*HWSZ)        // one (64,H,W) tensor, elems

enum { EPI_MSG=0, EPI_GATES=1, EPI_CAND=2 };

typedef __attribute__((ext_vector_type(8))) _Float16 f16x8;
typedef __attribute__((ext_vector_type(4))) float f32x4;
typedef __attribute__((ext_vector_type(4))) unsigned int uint4v;
typedef __attribute__((ext_vector_type(4))) unsigned short ushort4v;

__device__ __forceinline__ unsigned short f2h(float f) {
    _Float16 h = (_Float16)f;                    // v_cvt_f16_f32 (RTE)
    return __builtin_bit_cast(unsigned short, h);
}
__device__ __forceinline__ float h2f(unsigned short u) {
    return (float)__builtin_bit_cast(_Float16, u);
}

// global->LDS DMA, 16B per lane. LDS dest = wave-uniform base + lane*16.
__device__ __forceinline__ void load_lds16(const unsigned short* g,
                                           unsigned short* l) {
    __builtin_amdgcn_global_load_lds(
        (const __attribute__((address_space(1))) unsigned int*)g,
        (__attribute__((address_space(3))) unsigned int*)l, 16, 0, 0);
}

// Prepack conv weights to f16, LDS-ready lane-major CF=2 layout:
// chunk(cogrp32,kb) = [sh(9)][cf(2)][lane(64)][8ch] = 9216 f16 (18432 B).
// lane = q*16+n16 -> co = cogrp*32 + cf*16+n16, ch = q*8+j.
// Sections: msg 2x4 @0 | gates 4x6 @73728 | cand 2x6 @294912.
__global__ void prepack_k(const float* __restrict__ mw,
                          const float* __restrict__ gw,
                          const float* __restrict__ cw,
                          unsigned short* __restrict__ pw)
{
    const int MSG_I = 8*9216;         // 73728
    const int GAT_I = 24*9216;        // 221184
    const int CAN_I = 12*9216;        // 110592
    const int TOTAL = MSG_I + GAT_I + CAN_I;   // 405504
    int idx = blockIdx.x*256 + threadIdx.x;
    if (idx >= TOTAL) return;
    const float* w; int cin, nkb, rel; unsigned short* base;
    if (idx < MSG_I)              { w=mw; cin=128; nkb=4; rel=idx;             base=pw; }
    else if (idx < MSG_I+GAT_I)   { w=gw; cin=192; nkb=6; rel=idx-MSG_I;       base=pw+73728; }
    else                          { w=cw; cin=192; nkb=6; rel=idx-MSG_I-GAT_I; base=pw+294912; }
    int chunk = rel / 9216, r = rel - chunk*9216;
    int j = r & 7, lane = (r >> 3) & 63, cfsh = r >> 9;   // 0..17
    int cf = cfsh & 1, sh = cfsh >> 1;
    int q = lane >> 4, n16 = lane & 15;
    int co_l = cf*16 + n16, ch = q*8 + j;
    int cogrp = chunk / nkb, kb = chunk - cogrp*nkb;
    float f = w[(((long)(cogrp*32 + co_l))*cin + kb*32 + ch)*9 + sh];
    base[(size_t)chunk*9216 + r] = f2h(f);
}

// Convert x (2 agents x 4 t) fp32 planar -> f16 interleaved [t][half][pix][32].
__global__ void convert_all_k(const float* __restrict__ x,
                              unsigned short* __restrict__ xb0_all,
                              unsigned short* __restrict__ xb1_all)
{
    int idx = blockIdx.x*256 + threadIdx.x;      // 4,505,600 total
    int cp   = idx & 15;
    int rest = idx >> 4;
    int px4  = rest % 17600;
    int r2   = rest / 17600;                      // 0..15
    int hb = r2 & 1, ag = (r2 >> 1) & 1, t = r2 >> 2;
    const float* src = x + ((size_t)(ag*4 + t))*CHW
                         + (size_t)(hb*32 + 2*cp)*HWSZ + (size_t)px4*4;
    float4 a = *(const float4*)src;
    float4 b = *(const float4*)(src + HWSZ);
    unsigned int* dst = (unsigned int*)((ag ? xb1_all : xb0_all)
                        + (size_t)t*CHW + (size_t)hb*HWSZ*32) + (size_t)px4*64 + cp;
    dst[0]  = (unsigned)f2h(a.x) | ((unsigned)f2h(b.x) << 16);
    dst[16] = (unsigned)f2h(a.y) | ((unsigned)f2h(b.y) << 16);
    dst[32] = (unsigned)f2h(a.z) | ((unsigned)f2h(b.z) << 16);
    dst[48] = (unsigned)f2h(a.w) | ((unsigned)f2h(b.w) << 16);
}

// Block: 32 out-ch x (8 rows x 32 cols), 256 thr = 4 waves; wave w = rows
// 2w,2w+1.  LDS: weights dbuf 2x[9][2][64][8ch] = 36864 B -> 4 blocks/CU
// (16 waves).  B-frags read directly from global (coalesced 1KB/wave,
// L1/L2-served).  One __syncthreads per kb; weight DMA for kb+1 issued
// right after the barrier, drains at the NEXT barrier (a full compute
// phase later).
template<int EPI>
__global__ __launch_bounds__(256, 4)
void conv_mfma_k(const unsigned short* __restrict__ seg0b,
                 const unsigned short* __restrict__ seg1b,
                 const unsigned short* __restrict__ seg2b,
                 int nkb, int nkb_stride, int grp_base,
                 const unsigned short* __restrict__ pw,
                 const float* __restrict__ bias,
                 const unsigned short* e_hb,     // f16 interl. h_{t-1} (null @t=0)
                 const unsigned short* __restrict__ e_updb, // CAND: upd f16 interl.
                 float* out_f,                   // CAND: out[t] fp32 planar
                 unsigned short* out_b,          // MSG: aggb(t<3) GATES: rhb CAND: hb
                 unsigned short* out_b2)         // MSG: aggb3    GATES: updb
{
    __shared__ unsigned short s_w0[9216];      // [sh][cf][lane][8ch] 18432 B
    __shared__ unsigned short s_w1[9216];

    const int tid  = threadIdx.x;
    const int lane = tid & 63;
    const int wv   = tid >> 6;                 // 0..3
    const int n16  = lane & 15;
    const int q    = lane >> 4;

    int grp, ts = 0;
    if (EPI == EPI_MSG) { ts = blockIdx.z; grp = blockIdx.x & 1; }
    else                { grp = (blockIdx.x & 1) + 2*blockIdx.z + grp_base; }

    const unsigned short* s0 = seg0b + (EPI==EPI_MSG ? (size_t)ts*CHW : 0);
    const unsigned short* s1 = seg1b + (EPI==EPI_MSG ? (size_t)ts*CHW : 0);
    unsigned short* ob = out_b;
    if (EPI == EPI_MSG) ob = (ts < 3) ? out_b + (size_t)ts*CHW : out_b2;

    const int x0p = (blockIdx.x >> 1) * 32;
    const int y0  = blockIdx.y * 8;
    const bool ledge = (x0p == 0);
    const bool redge = (x0p + 32 == WW);

    // per-lane column base offsets (u16 units), p-parity 0/1
    const int cb0 = n16*32 + q*8;
    const int cb1 = (16 + n16)*32 + q*8;

    auto srcof = [&](int kb) -> const unsigned short* {
        return ((kb < 2) ? s0 : (kb < 4) ? s1 : seg2b) + (size_t)(kb & 1)*HWSZ*32;
    };
    auto stage_w = [&](int kb, unsigned short* bw) {
        const unsigned short* wsrc = pw + (size_t)(grp*nkb_stride + kb)*9216;
#pragma unroll
        for (int i = 0; i < 5; ++i) {
            const int u = wv + 4*i;            // 0..19, skip >=18
            if (u < 18)
                load_lds16(wsrc + (size_t)u*512 + (size_t)lane*8, &bw[(size_t)u*512]);
        }
    };

    f32x4 acc[2][4];
#pragma unroll
    for (int cf=0; cf<2; ++cf)
#pragma unroll
        for (int p=0; p<4; ++p) acc[cf][p] = (f32x4){0.f,0.f,0.f,0.f};

    const f16x8 zfrag = __builtin_bit_cast(f16x8, (uint4v){0u,0u,0u,0u});

    auto compute = [&](int kb, const unsigned short* swt) {
        const unsigned short* src = srcof(kb);
#pragma unroll
        for (int ky = 0; ky < 3; ++ky) {
#pragma unroll
            for (int kx = 0; kx < 3; ++kx) {
                const int sh = ky*3 + kx;
                f16x8 aw0 = *(const f16x8*)&swt[((sh*2 + 0)*64 + lane)*8];
                f16x8 aw1 = *(const f16x8*)&swt[((sh*2 + 1)*64 + lane)*8];
#pragma unroll
                for (int p = 0; p < 4; ++p) {
                    const int row = y0 + 2*wv + (p >> 1) + ky - 1;
                    f16x8 bfr = zfrag;
                    if ((unsigned)row < (unsigned)HH) {
                        int off = (row*WW + x0p + kx - 1)*32 + ((p & 1) ? cb1 : cb0);
                        const bool need_mask = (p & 1) ? (redge && kx == 2)
                                                       : (ledge && kx == 0);
                        if (need_mask) {
                            const int col = x0p + 16*(p & 1) + n16 + kx - 1;
                            const bool cv = (unsigned)col < (unsigned)WW;
                            off = off < 0 ? 0 : off;       // clamp (col=-1,row=0)
                            f16x8 t = *(const f16x8*)(src + off);
                            bfr = cv ? t : bfr;
                        } else {
                            bfr = *(const f16x8*)(src + off);
                        }
                    }
                    acc[0][p] = __builtin_amdgcn_mfma_f32_16x16x32_f16(aw0, bfr, acc[0][p], 0, 0, 0);
                    acc[1][p] = __builtin_amdgcn_mfma_f32_16x16x32_f16(aw1, bfr, acc[1][p], 0, 0, 0);
                }
            }
        }
    };

    // ---- weight pipeline: dbuf, 1 barrier per kb, DMA flies over compute
    stage_w(0, s_w0);
    for (int kb = 0; kb < nkb; kb += 2) {      // nkb even (4 or 6)
        __syncthreads();                       // s_w0(kb) DMAs landed
        stage_w(kb + 1, s_w1);
        __builtin_amdgcn_sched_barrier(0);
        compute(kb, s_w0);
        __syncthreads();                       // s_w1(kb+1) landed (flew over compute)
        if (kb + 2 < nkb) stage_w(kb + 2, s_w0);
        __builtin_amdgcn_sched_barrier(0);
        compute(kb + 1, s_w1);
    }

    // ---- epilogue. C/D: pixel = lane&15, co = (lane>>4)*4 + reg
#pragma unroll
    for (int cf = 0; cf < 2; ++cf) {
        const int co_r0 = grp*32 + cf*16 + q*4;    // global co of reg 0
        const int half  = (co_r0 >> 5) & 1;
        const int cmod  = co_r0 & 31;
#pragma unroll
        for (int p = 0; p < 4; ++p) {
            const int row = y0 + 2*wv + (p >> 1);
            const int col = x0p + 16*(p & 1) + n16;
            if (row >= HH) continue;
            const long pix = (long)row*WW + col;
            const size_t iidx = (((size_t)half*HWSZ + pix) << 5) + cmod;
            float v[4];
#pragma unroll
            for (int r = 0; r < 4; ++r) v[r] = acc[cf][p][r] + bias[co_r0 + r];

            if (EPI == EPI_MSG) {
                ushort4v xv = *(const ushort4v*)&s0[iidx];
                ushort4v s;
#pragma unroll
                for (int r = 0; r < 4; ++r)
                    s[r] = f2h(0.5f*(h2f(xv[r]) + v[r]));
                *(ushort4v*)&ob[iidx] = s;
            } else if (EPI == EPI_GATES) {
                if (co_r0 < 64) {   // reset -> rh = sigmoid * h (f16 interl.)
                    ushort4v hv = e_hb ? *(const ushort4v*)&e_hb[iidx]
                                       : (ushort4v){0,0,0,0};
                    ushort4v s;
#pragma unroll
                    for (int r = 0; r < 4; ++r) {
                        float g = 1.f/(1.f + __expf(-v[r]));
                        s[r] = f2h(g * h2f(hv[r]));
                    }
                    *(ushort4v*)&out_b[iidx] = s;
                } else {            // update -> updb (f16 interleaved)
                    const int cu = co_r0 - 64;
                    const size_t uidx = (((size_t)(cu >> 5)*HWSZ + pix) << 5) + (cu & 31);
                    ushort4v s;
#pragma unroll
                    for (int r = 0; r < 4; ++r)
                        s[r] = f2h(1.f/(1.f + __expf(-v[r])));
                    *(ushort4v*)&out_b2[uidx] = s;
                }
            } else {                // CAND: h_next -> out fp32 planar + hb f16
                ushort4v uv = *(const ushort4v*)&e_updb[iidx];
                ushort4v hv = e_hb ? *(const ushort4v*)&e_hb[iidx]
                                   : (ushort4v){0,0,0,0};
                ushort4v s;
#pragma unroll
                for (int r = 0; r < 4; ++r) {
                    float cnm = tanhf(v[r]);
                    float u   = h2f(uv[r]);
                    float hn  = (1.f - u)*h2f(hv[r]) + u*cnm;
                    out_f[(long)(co_r0 + r)*HWSZ + pix] = hn;
                    s[r] = f2h(hn);
                }
                *(ushort4v*)&out_b[iidx] = s;
            }
        }
    }
}

// ws (u16 units): xb0_all 4C | aggb3 C | rhb C | updb C | hb C | pw 405504
//   = 72.9 MB.   d_out aliases: xb1_all = out[0..1] (dead until step 0
//   writes out[0]), aggb[0..2] = out[2..3].
extern "C" void kernel_launch(void* const* d_in, const int* in_sizes, int n_in,
                              void* d_out, int out_size, void* d_ws, size_t ws_size,
                              hipStream_t stream)
{
    const float* x       = (const float*)d_in[0];
    const float* msg_w   = (const float*)d_in[1];
    const float* msg_b   = (const float*)d_in[2];
    const float* gates_w = (const float*)d_in[3];
    const float* gates_b = (const float*)d_in[4];
    const float* can_w   = (const float*)d_in[5];
    const float* can_b   = (const float*)d_in[6];
    float* out = (float*)d_out;

    unsigned short* W       = (unsigned short*)d_ws;
    unsigned short* xb0_all = W;                  // [4][2][HWSZ][32]
    unsigned short* aggb3   = W + 4*CHW;
    unsigned short* rhb     = W + 5*CHW;
    unsigned short* updb    = W + 6*CHW;
    unsigned short* hb      = W + 7*CHW;
    unsigned short* pw      = W + 8*CHW;          // 405504 u16
    unsigned short* pw_msg  = pw;                 // cf2 msg   (2x4)
    unsigned short* pw_gat  = pw + 73728;         // cf2 gates (4x6)
    unsigned short* pw_can  = pw + 294912;        // cf2 cand  (2x6)

    unsigned short* outU16   = (unsigned short*)d_out;
    unsigned short* xb1_all  = outU16;            // 4*CHW u16 = out[0..1]
    unsigned short* aggbase  = outU16 + 4*CHW;    // aggb[0..2] = out[2..3]

    prepack_k<<<dim3(1584), dim3(256), 0, stream>>>(msg_w, gates_w, can_w, pw);
    convert_all_k<<<dim3(17600), dim3(256), 0, stream>>>(x, xb0_all, xb1_all);

    // msg for all 4 t in one dispatch: Cin=[x0|x1], Cout=64 -> aggb[t].
    // grid x = tile_x*2 + grp (co-twins adjacent), z = t: 2200 blocks.
    conv_mfma_k<EPI_MSG><<<dim3(22,25,4), dim3(256), 0, stream>>>(
        xb0_all, xb1_all, nullptr, 4, 4, 0, pw_msg, msg_b,
        nullptr, nullptr, nullptr, aggbase, aggb3);

    for (int t = 0; t < 4; ++t) {
        const unsigned short* xt  = xb0_all + (size_t)t*CHW;
        const unsigned short* agt = (t < 3) ? aggbase + (size_t)t*CHW : aggb3;
        const unsigned short* hprev = t ? hb : nullptr;

        if (t == 0) {
            // t=0: h==0 -> reset*h==0 and CAND(nkb=4) never reads rhb;
            // update half only: grp = 2 + (bx&1), nkb=4. 550 blocks.
            conv_mfma_k<EPI_GATES><<<dim3(22,25,1), dim3(256), 0, stream>>>(
                xt, agt, nullptr, 4, 6, 2, pw_gat, gates_b,
                nullptr, nullptr, nullptr, rhb, updb);
        } else {
            // gates: Cin=[x|agg|h], Cout=128; grp = (bx&1)+2z in 0..3.
            // 1100 blocks.
            conv_mfma_k<EPI_GATES><<<dim3(22,25,2), dim3(256), 0, stream>>>(
                xt, agt, hb, 6, 6, 0, pw_gat, gates_b,
                hprev, nullptr, nullptr, rhb, updb);
        }
        // cand: Cin=[x|agg|rh], Cout=64 -> out[t] fp32 + hb f16.
        // grp = bx&1 in {0,1}: 550 blocks.
        conv_mfma_k<EPI_CAND><<<dim3(22,25,1), dim3(256), 0, stream>>>(
            xt, agt, rhb, t ? 6 : 4, 6, 0, pw_can, can_b,
            hprev, updb, out + (size_t)t*CHW, hb, nullptr);
    }
}

// Round 9
// 572.165 us; speedup vs baseline: 1.5456x; 1.5456x over previous
//
#include <hip/hip_runtime.h>
#include <math.h>
#include <string.h>

// V2VNetFusion on MI355X, round 13: r9 structure + NW template.
// Evidence: r9's CF=4 / 8-row / 2-blocks-per-CU pipelined config is the
// best measured for wide dispatches; r9's entire remaining cost was CAND
// (275 blocks = 1.07/CU, 82us @ MfmaUtil 4.7%). r10/r11's CF=2 fix hit
// the CF=2 LDS-read ratio ceiling (~20% MfmaUtil = 349 MFMA-cy /1728
// LDS-cy). r12 proved MFMA operands must stream from LDS, not global.
// Fix that keeps both properties: smaller TILE, same co-blocking.
// NW template = waves/block; tile = (2*NW) rows x 32 cols, CF=4 always:
//   NW=4 (256 thr, 8-row, 80384B LDS): MSG, GATES t>0  (1100/550 blocks)
//   NW=2 (128 thr, 4-row, 62976B LDS): CAND, GATES t0  (550 blocks)
// Per-wave code identical (P=4: 2 rows x 2 col-halves); ratio 0.30 kept;
// 2 blocks/CU everywhere; input double-buffered + pipelined, weights
// single-buffered (drain hidden by co-resident block).
#define HH 200
#define WW 352
#define HWSZ (HH*WW)          // 70400
#define CHW (64L*HWSZ)        // one (64,H,W) tensor, elems

enum { EPI_MSG=0, EPI_GATES=1, EPI_CAND=2 };

typedef __attribute__((ext_vector_type(8))) _Float16 f16x8;
typedef __attribute__((ext_vector_type(4))) float f32x4;
typedef __attribute__((ext_vector_type(4))) unsigned int uint4v;
typedef __attribute__((ext_vector_type(4))) unsigned short ushort4v;

__device__ __forceinline__ unsigned short f2h(float f) {
    _Float16 h = (_Float16)f;                    // v_cvt_f16_f32 (RTE)
    return __builtin_bit_cast(unsigned short, h);
}
__device__ __forceinline__ float h2f(unsigned short u) {
    return (float)__builtin_bit_cast(_Float16, u);
}

// global->LDS DMA, 16B per lane. LDS dest = wave-uniform base + lane*16.
__device__ __forceinline__ void load_lds16(const unsigned short* g,
                                           unsigned short* l) {
    __builtin_amdgcn_global_load_lds(
        (const __attribute__((address_space(1))) unsigned int*)g,
        (__attribute__((address_space(3))) unsigned int*)l, 16, 0, 0);
}

// Prepack conv weights to f16, LDS-ready lane-major layout, CF=4:
// chunk(cogrp64,kb) = [sh(9)][cf(4)][lane(64)][8ch] = 18432 f16.
// lane = q*16+n16 -> co = cogrp*64 + cf*16+n16, ch = q*8+j.
// msg: 1x4, gates: 2x6, cand: 1x6 chunks. Tail threads zero the 256B
// zero-page (reg source for OOB halo).
__global__ void prepack_k(const float* __restrict__ mw,
                          const float* __restrict__ gw,
                          const float* __restrict__ cw,
                          unsigned short* __restrict__ pw,
                          unsigned short* __restrict__ zp)
{
    const int MSG_I = 4*18432;        // 73728
    const int GAT_I = 12*18432;       // 221184
    const int CAN_I = 6*18432;        // 110592
    const int TOTAL = MSG_I + GAT_I + CAN_I;   // 405504
    int idx = blockIdx.x*256 + threadIdx.x;
    if (idx >= TOTAL) {
        int r = idx - TOTAL;
        if (r < 128) zp[r] = 0;
        return;
    }
    const float* w; int cin, nkb, rel; unsigned short* base;
    if (idx < MSG_I)              { w=mw; cin=128; nkb=4; rel=idx;              base=pw; }
    else if (idx < MSG_I+GAT_I)   { w=gw; cin=192; nkb=6; rel=idx-MSG_I;        base=pw+73728; }
    else                          { w=cw; cin=192; nkb=6; rel=idx-MSG_I-GAT_I;  base=pw+294912; }
    int chunk = rel / 18432, r = rel - chunk*18432;
    int j = r & 7, lane = (r >> 3) & 63, cfsh = r >> 9;   // cfsh 0..35
    int cf = cfsh & 3, sh = cfsh >> 2;
    int q = lane >> 4, n16 = lane & 15;
    int co_l = cf*16 + n16, ch = q*8 + j;
    int cogrp = chunk / nkb, kb = chunk - cogrp*nkb;
    float f = w[(((long)(cogrp*64 + co_l))*cin + kb*32 + ch)*9 + sh];
    base[(size_t)chunk*18432 + r] = f2h(f);
}

// Convert x (2 agents x 4 t) fp32 planar -> f16 interleaved [t][half][pix][32].
__global__ void convert_all_k(const float* __restrict__ x,
                              unsigned short* __restrict__ xb0_all,
                              unsigned short* __restrict__ xb1_all)
{
    int idx = blockIdx.x*256 + threadIdx.x;      // 4,505,600 total
    int cp   = idx & 15;
    int rest = idx >> 4;
    int px4  = rest % 17600;
    int r2   = rest / 17600;                      // 0..15
    int hb = r2 & 1, ag = (r2 >> 1) & 1, t = r2 >> 2;
    const float* src = x + ((size_t)(ag*4 + t))*CHW
                         + (size_t)(hb*32 + 2*cp)*HWSZ + (size_t)px4*4;
    float4 a = *(const float4*)src;
    float4 b = *(const float4*)(src + HWSZ);
    unsigned int* dst = (unsigned int*)((ag ? xb1_all : xb0_all)
                        + (size_t)t*CHW + (size_t)hb*HWSZ*32) + (size_t)px4*64 + cp;
    dst[0]  = (unsigned)f2h(a.x) | ((unsigned)f2h(b.x) << 16);
    dst[16] = (unsigned)f2h(a.y) | ((unsigned)f2h(b.y) << 16);
    dst[32] = (unsigned)f2h(a.z) | ((unsigned)f2h(b.z) << 16);
    dst[48] = (unsigned)f2h(a.w) | ((unsigned)f2h(b.w) << 16);
}

// Block: 64 out-ch x (2*NW rows x 32 cols), 64*NW threads = NW waves;
// wave wv = rows 2wv,2wv+1 (P=4: 2 rows x 2 col-halves), CF=4.
// LDS: 2x input [(2NW+2)][34][32] f16 XOR-swz + 1x weights
// [9][4][64][8] (36864 B).  NW=4: 80384 B, NW=2: 62976 B -> 2 blocks/CU.
template<int EPI, int NW>
__global__ __launch_bounds__(64*NW, 2)
void conv_mfma_k(const unsigned short* __restrict__ seg0b,
                 const unsigned short* __restrict__ seg1b,
                 const unsigned short* __restrict__ seg2b,
                 int nkb, int nkb_stride, int grp_base,
                 const unsigned short* __restrict__ pw,
                 const unsigned short* __restrict__ zp,
                 const float* __restrict__ bias,
                 const unsigned short* e_hb,     // f16 interl. h_{t-1} (null @t=0)
                 const unsigned short* __restrict__ e_updb, // CAND: upd f16 interl.
                 float* out_f,                   // CAND: out[t] fp32 planar
                 unsigned short* out_b,          // MSG: aggb(t<3) GATES: rhb CAND: hb
                 unsigned short* out_b2)         // MSG: aggb3    GATES: updb
{
    constexpr int ROWS    = 2*NW;
    constexpr int THREADS = 64*NW;
    constexpr int POS     = (ROWS+2)*34;         // tile positions incl. halo
    constexpr int HPOS    = 68 + 4*NW;           // halo-ring positions
    constexpr int HSLOTS  = HPOS*4;              // 16B granules in ring
    constexpr int NH      = (HSLOTS + THREADS - 1)/THREADS;

    __shared__ unsigned short s_in0[POS*32];
    __shared__ unsigned short s_in1[POS*32];
    __shared__ unsigned short s_w[9*4*64*8];     // 36864 B

    const int tid  = threadIdx.x;
    const int lane = tid & 63;
    const int wv   = tid >> 6;                   // 0..NW-1
    const int n16  = lane & 15;
    const int q    = lane >> 4;

    int grp, ts = 0;
    if (EPI == EPI_MSG) { ts = blockIdx.z; grp = 0; }
    else                { grp = blockIdx.z + grp_base; }

    const unsigned short* s0 = seg0b + (EPI==EPI_MSG ? (size_t)ts*CHW : 0);
    const unsigned short* s1 = seg1b + (EPI==EPI_MSG ? (size_t)ts*CHW : 0);
    unsigned short* ob = out_b;
    if (EPI == EPI_MSG) ob = (ts < 3) ? out_b + (size_t)ts*CHW : out_b2;

    const int x0p = blockIdx.x * 32;
    const int y0  = blockIdx.y * ROWS;

    // ---- halo descriptors: ring = HPOS pos x 4 granules, NH per thread.
    int hdst[NH]; size_t hsrc[NH]; bool hact[NH], hval[NH];
#pragma unroll
    for (int b = 0; b < NH; ++b) {
        const int s = tid + b*THREADS;
        hact[b] = (s < HSLOTS); hval[b] = false; hdst[b] = 0; hsrc[b] = 0;
        if (hact[b]) {
            int hp = s >> 2, gs = s & 3;
            int row, col;
            if (hp < 34)      { row = 0;      col = hp; }
            else if (hp < 68) { row = ROWS+1; col = hp - 34; }
            else { int k = hp - 68; row = 1 + (k >> 1); col = (k & 1) * 33; }
            int pos = row*34 + col;
            int gy = y0 + row - 1, gx = x0p + col - 1;
            hdst[b] = (pos << 5) + (gs << 3);
            int g = (gs ^ pos ^ (pos >> 2)) & 3;
            if ((unsigned)gy < (unsigned)HH && (unsigned)gx < (unsigned)WW) {
                hval[b] = true;
                hsrc[b] = ((size_t)(gy*WW + gx) << 5) + (size_t)(g << 3);
            }
        }
    }

    auto srcof = [&](int kb) -> const unsigned short* {
        return ((kb < 2) ? s0 : (kb < 4) ? s1 : seg2b) + (size_t)(kb & 1)*HWSZ*32;
    };

    struct HV { uint4v v[NH]; };
    auto halo_load = [&](int kb, HV& h) {
        const unsigned short* src = srcof(kb);
#pragma unroll
        for (int b = 0; b < NH; ++b)
            if (hact[b]) h.v[b] = *(const uint4v*)(hval[b] ? src + hsrc[b] : zp);
    };
    auto halo_write = [&](unsigned short* bin, const HV& h) {
#pragma unroll
        for (int b = 0; b < NH; ++b)
            if (hact[b]) *(uint4v*)&bin[hdst[b]] = h.v[b];
    };

    // interior: ROWS x 2 col-halves = 4*NW wave-chunks, 4 per wave
    // (full 64B granules, inverse-swizzled source, linear LDS dest).
    auto stage_in = [&](int kb, unsigned short* bin) {
        const unsigned short* src = srcof(kb);
#pragma unroll
        for (int j = 0; j < 4; ++j) {
            const int c    = wv + NW*j;          // 0..2*ROWS-1
            const int row  = 1 + (c >> 1);       // 1..ROWS
            const int colh = c & 1;
            const int gy   = y0 + row - 1;       // in [0,199] always
            const int p0   = row*34 + 1 + colh*16;
            const int pl   = p0 + (lane >> 2);
            const int g    = ((lane & 3) ^ pl ^ (pl >> 2)) & 3;
            const int gx   = x0p + colh*16 + (lane >> 2);
            load_lds16(src + (((size_t)(gy*WW + gx)) << 5) + (g << 3),
                       &bin[(size_t)p0 << 5]);
        }
    };
    auto stage_w = [&](int kb) {
        const unsigned short* wsrc = pw + (size_t)(grp*nkb_stride + kb)*18432;
#pragma unroll
        for (int i = 0; i < 36/NW; ++i) {
            const int u = wv + NW*i;             // 0..35 exactly
            load_lds16(wsrc + (size_t)u*512 + (size_t)lane*8, &s_w[(size_t)u*512]);
        }
    };

    f32x4 acc[4][4];
#pragma unroll
    for (int cf=0; cf<4; ++cf)
#pragma unroll
        for (int p=0; p<4; ++p) acc[cf][p] = (f32x4){0.f,0.f,0.f,0.f};

    auto compute = [&](const unsigned short* sin) {
#pragma unroll
        for (int ky = 0; ky < 3; ++ky) {
#pragma unroll
            for (int kx = 0; kx < 3; ++kx) {
                const int sh = ky*3 + kx;
                f16x8 aw[4];
#pragma unroll
                for (int cf = 0; cf < 4; ++cf)
                    aw[cf] = *(const f16x8*)&s_w[((sh*4 + cf)*64 + lane)*8];
#pragma unroll
                for (int p = 0; p < 4; ++p) {
                    const int rl = 2*wv + (p >> 1) + ky;
                    const int cl = 16*(p & 1) + n16 + kx;
                    const int pos = rl*34 + cl;
                    const int sw = (q ^ pos ^ (pos >> 2)) & 3;
                    f16x8 bfr = *(const f16x8*)&sin[(pos << 5) + (sw << 3)];
#pragma unroll
                    for (int cf = 0; cf < 4; ++cf)
                        acc[cf][p] = __builtin_amdgcn_mfma_f32_16x16x32_f16(
                                         aw[cf], bfr, acc[cf][p], 0, 0, 0);
                }
            }
        }
    };

    HV h0, h1;
    stage_in(0, s_in0);          // prologue: kb=0 input + weights + halo
    stage_w(0);
    halo_load(0, h0);

    for (int kb = 0; kb < nkb; kb += 2) {      // nkb even (4 or 6)
        // ===== phase A: buf0 = kb
        halo_write(s_in0, h0);                 // waits h0 (vmcnt dep)
        __syncthreads();                       // kb in+w DMAs landed, halo visible
        halo_load(kb + 1, h1);
        stage_in(kb + 1, s_in1);               // flies across compute
        __builtin_amdgcn_sched_barrier(0);
        compute(s_in0);
        __syncthreads();                       // all waves done reading s_w(kb)
        stage_w(kb + 1);
        // ===== phase B: buf1 = kb+1
        halo_write(s_in1, h1);
        __syncthreads();                       // kb+1 in+w DMAs landed
        if (kb + 2 < nkb) {
            halo_load(kb + 2, h0);
            stage_in(kb + 2, s_in0);
            __builtin_amdgcn_sched_barrier(0);
        }
        compute(s_in1);
        __syncthreads();
        if (kb + 2 < nkb) stage_w(kb + 2);
    }

    // ---- epilogue. C/D: pixel = lane&15, co = (lane>>4)*4 + reg
#pragma unroll
    for (int cf = 0; cf < 4; ++cf) {
        const int half   = cf >> 1;                // 32-ch half within co64
        const int cobase = grp*64 + cf*16 + q*4;   // global co of reg 0
        const int cmod   = (cf & 1)*16 + q*4;      // co within 32-plane
#pragma unroll
        for (int p = 0; p < 4; ++p) {
            const int row = y0 + 2*wv + (p >> 1);
            const int col = x0p + 16*(p & 1) + n16;
            if (row >= HH) continue;
            const long pix = (long)row*WW + col;
            const size_t iidx = (((size_t)half*HWSZ + pix) << 5) + cmod;
            float v[4];
#pragma unroll
            for (int r = 0; r < 4; ++r) v[r] = acc[cf][p][r] + bias[cobase + r];

            if (EPI == EPI_MSG) {
                ushort4v xv = *(const ushort4v*)&s0[iidx];
                ushort4v s;
#pragma unroll
                for (int r = 0; r < 4; ++r)
                    s[r] = f2h(0.5f*(h2f(xv[r]) + v[r]));
                *(ushort4v*)&ob[iidx] = s;
            } else if (EPI == EPI_GATES) {
                if (grp == 0) {  // reset block -> rh = sigmoid * h
                    ushort4v hv = e_hb ? *(const ushort4v*)&e_hb[iidx]
                                       : (ushort4v){0,0,0,0};
                    ushort4v s;
#pragma unroll
                    for (int r = 0; r < 4; ++r) {
                        float g = 1.f/(1.f + __expf(-v[r]));
                        s[r] = f2h(g * h2f(hv[r]));
                    }
                    *(ushort4v*)&out_b[iidx] = s;
                } else {         // update block -> updb
                    ushort4v s;
#pragma unroll
                    for (int r = 0; r < 4; ++r)
                        s[r] = f2h(1.f/(1.f + __expf(-v[r])));
                    *(ushort4v*)&out_b2[iidx] = s;
                }
            } else {             // CAND: h_next -> out fp32 planar + hb f16
                ushort4v uv = *(const ushort4v*)&e_updb[iidx];
                ushort4v hv = e_hb ? *(const ushort4v*)&e_hb[iidx]
                                   : (ushort4v){0,0,0,0};
                ushort4v s;
#pragma unroll
                for (int r = 0; r < 4; ++r) {
                    float cnm = tanhf(v[r]);
                    float u   = h2f(uv[r]);
                    float hn  = (1.f - u)*h2f(hv[r]) + u*cnm;
                    out_f[(long)(cobase+r)*HWSZ + pix] = hn;
                    s[r] = f2h(hn);
                }
                *(ushort4v*)&out_b[iidx] = s;
            }
        }
    }
}

// ws (u16 units): xb0_all 4C | aggb3 C | rhb C | updb C | hb C | pw 405504
//   | zp 128  = 72.9 MB.   d_out aliases: xb1_all = out[0..1] (dead until
//   step 0 writes out[0]), aggb[0..2] = out[2..3].
extern "C" void kernel_launch(void* const* d_in, const int* in_sizes, int n_in,
                              void* d_out, int out_size, void* d_ws, size_t ws_size,
                              hipStream_t stream)
{
    const float* x       = (const float*)d_in[0];
    const float* msg_w   = (const float*)d_in[1];
    const float* msg_b   = (const float*)d_in[2];
    const float* gates_w = (const float*)d_in[3];
    const float* gates_b = (const float*)d_in[4];
    const float* can_w   = (const float*)d_in[5];
    const float* can_b   = (const float*)d_in[6];
    float* out = (float*)d_out;

    unsigned short* W       = (unsigned short*)d_ws;
    unsigned short* xb0_all = W;                  // [4][2][HWSZ][32]
    unsigned short* aggb3   = W + 4*CHW;
    unsigned short* rhb     = W + 5*CHW;
    unsigned short* updb    = W + 6*CHW;
    unsigned short* hb      = W + 7*CHW;
    unsigned short* pw      = W + 8*CHW;          // 405504 u16
    unsigned short* pw_msg  = pw;                 // cf4 msg   (1x4)
    unsigned short* pw_gat  = pw + 73728;         // cf4 gates (2x6)
    unsigned short* pw_can  = pw + 294912;        // cf4 cand  (1x6)
    unsigned short* zp      = pw + 405504;        // 128 u16 zero page

    unsigned short* outU16   = (unsigned short*)d_out;
    unsigned short* xb1_all  = outU16;            // 4*CHW u16 = out[0..1]
    unsigned short* aggbase  = outU16 + 4*CHW;    // aggb[0..2] = out[2..3]

    prepack_k<<<dim3(1585), dim3(256), 0, stream>>>(msg_w, gates_w, can_w, pw, zp);
    convert_all_k<<<dim3(17600), dim3(256), 0, stream>>>(x, xb0_all, xb1_all);

    // msg for all 4 t in one dispatch: Cin=[x0|x1], Cout=64 -> aggb[t].
    // NW=4: 1100 blocks (2/CU healthy).
    conv_mfma_k<EPI_MSG,4><<<dim3(11,25,4), dim3(256), 0, stream>>>(
        xb0_all, xb1_all, nullptr, 4, 4, 0, pw_msg, zp, msg_b,
        nullptr, nullptr, nullptr, aggbase, aggb3);

    for (int t = 0; t < 4; ++t) {
        const unsigned short* xt  = xb0_all + (size_t)t*CHW;
        const unsigned short* agt = (t < 3) ? aggbase + (size_t)t*CHW : aggb3;
        const unsigned short* hprev = t ? hb : nullptr;

        if (t == 0) {
            // t=0: h==0 -> reset*h==0 and CAND(nkb=4) never reads rhb;
            // update half only (grp_base=1). NW=2 -> 550 blocks.
            conv_mfma_k<EPI_GATES,2><<<dim3(11,50,1), dim3(128), 0, stream>>>(
                xt, agt, nullptr, 4, 6, 1, pw_gat, zp, gates_b,
                nullptr, nullptr, nullptr, rhb, updb);
        } else {
            // gates: Cin=[x|agg|h], Cout=128; z=0 reset / z=1 update.
            // NW=4 -> 550 blocks.
            conv_mfma_k<EPI_GATES,4><<<dim3(11,25,2), dim3(256), 0, stream>>>(
                xt, agt, hb, 6, 6, 0, pw_gat, zp, gates_b,
                hprev, nullptr, nullptr, rhb, updb);
        }
        // cand: Cin=[x|agg|rh], Cout=64 -> out[t] fp32 + hb f16.
        // NW=2 -> 550 blocks (fixes r9's 275-block latency hole).
        conv_mfma_k<EPI_CAND,2><<<dim3(11,50,1), dim3(128), 0, stream>>>(
            xt, agt, rhb, t ? 6 : 4, 6, 0, pw_can, zp, can_b,
            hprev, updb, out + (size_t)t*CHW, hb, nullptr);
    }
}

// Round 10
// 406.828 us; speedup vs baseline: 2.1737x; 1.4064x over previous
//
#include <hip/hip_runtime.h>
#include <math.h>
#include <string.h>

// V2VNetFusion on MI355X, round 14: r9 (428us, best) + WR row-split for
// the four 275-block dispatches.
// r13 post-mortem: NW=2 (128thr) at 63KB LDS -> 2 blk/CU x 2 waves =
// 4 waves/CU, same as r9's sick CAND, plus doubled per-block weight
// staging. waves/CU = blocks/CU x waves/block is THE lever (measured
// 4->190TF, 8->~450TF; HBM and LDS-throughput both far from binding).
// WR template: rows-per-wave.
//   WR=2: r9 verbatim. 256thr/4 waves, tile 8x32, P=4, LDS 80384,
//         2 blk/CU = 8 waves/CU.  MSG (1100 blk), GATES t>0 (550).
//   WR=1: 256thr/4 waves, tile 4x32, wave = 1 row x 32 col (P=2),
//         LDS = 2x26112(in) + 36864(w) = 62976 -> 2 blk/CU = 8 waves/CU,
//         grid 550.  CAND all t, GATES t0 (fixes the 275-block hole at
//         8 waves/CU instead of r13's 4).
#define HH 200
#define WW 352
#define HWSZ (HH*WW)          // 70400
#define CHW (64L*HWSZ)        // one (64,H,W) tensor, elems

enum { EPI_MSG=0, EPI_GATES=1, EPI_CAND=2 };

typedef __attribute__((ext_vector_type(8))) _Float16 f16x8;
typedef __attribute__((ext_vector_type(4))) float f32x4;
typedef __attribute__((ext_vector_type(4))) unsigned int uint4v;
typedef __attribute__((ext_vector_type(4))) unsigned short ushort4v;

__device__ __forceinline__ unsigned short f2h(float f) {
    _Float16 h = (_Float16)f;                    // v_cvt_f16_f32 (RTE)
    return __builtin_bit_cast(unsigned short, h);
}
__device__ __forceinline__ float h2f(unsigned short u) {
    return (float)__builtin_bit_cast(_Float16, u);
}

// global->LDS DMA, 16B per lane. LDS dest = wave-uniform base + lane*16.
__device__ __forceinline__ void load_lds16(const unsigned short* g,
                                           unsigned short* l) {
    __builtin_amdgcn_global_load_lds(
        (const __attribute__((address_space(1))) unsigned int*)g,
        (__attribute__((address_space(3))) unsigned int*)l, 16, 0, 0);
}

// Prepack conv weights to f16, LDS-ready lane-major layout, CF=4:
// chunk(cogrp64,kb) = [sh(9)][cf(4)][lane(64)][8ch] = 18432 f16.
// lane = q*16+n16 -> co = cogrp*64 + cf*16+n16, ch = q*8+j.
// msg: 1x4, gates: 2x6, cand: 1x6 chunks. Tail threads zero the 256B
// zero-page (reg source for OOB halo).
__global__ void prepack_k(const float* __restrict__ mw,
                          const float* __restrict__ gw,
                          const float* __restrict__ cw,
                          unsigned short* __restrict__ pw,
                          unsigned short* __restrict__ zp)
{
    const int MSG_I = 4*18432;        // 73728
    const int GAT_I = 12*18432;       // 221184
    const int CAN_I = 6*18432;        // 110592
    const int TOTAL = MSG_I + GAT_I + CAN_I;   // 405504
    int idx = blockIdx.x*256 + threadIdx.x;
    if (idx >= TOTAL) {
        int r = idx - TOTAL;
        if (r < 128) zp[r] = 0;
        return;
    }
    const float* w; int cin, nkb, rel; unsigned short* base;
    if (idx < MSG_I)              { w=mw; cin=128; nkb=4; rel=idx;              base=pw; }
    else if (idx < MSG_I+GAT_I)   { w=gw; cin=192; nkb=6; rel=idx-MSG_I;        base=pw+73728; }
    else                          { w=cw; cin=192; nkb=6; rel=idx-MSG_I-GAT_I;  base=pw+294912; }
    int chunk = rel / 18432, r = rel - chunk*18432;
    int j = r & 7, lane = (r >> 3) & 63, cfsh = r >> 9;   // cfsh 0..35
    int cf = cfsh & 3, sh = cfsh >> 2;
    int q = lane >> 4, n16 = lane & 15;
    int co_l = cf*16 + n16, ch = q*8 + j;
    int cogrp = chunk / nkb, kb = chunk - cogrp*nkb;
    float f = w[(((long)(cogrp*64 + co_l))*cin + kb*32 + ch)*9 + sh];
    base[(size_t)chunk*18432 + r] = f2h(f);
}

// Convert x (2 agents x 4 t) fp32 planar -> f16 interleaved [t][half][pix][32].
__global__ void convert_all_k(const float* __restrict__ x,
                              unsigned short* __restrict__ xb0_all,
                              unsigned short* __restrict__ xb1_all)
{
    int idx = blockIdx.x*256 + threadIdx.x;      // 4,505,600 total
    int cp   = idx & 15;
    int rest = idx >> 4;
    int px4  = rest % 17600;
    int r2   = rest / 17600;                      // 0..15
    int hb = r2 & 1, ag = (r2 >> 1) & 1, t = r2 >> 2;
    const float* src = x + ((size_t)(ag*4 + t))*CHW
                         + (size_t)(hb*32 + 2*cp)*HWSZ + (size_t)px4*4;
    float4 a = *(const float4*)src;
    float4 b = *(const float4*)(src + HWSZ);
    unsigned int* dst = (unsigned int*)((ag ? xb1_all : xb0_all)
                        + (size_t)t*CHW + (size_t)hb*HWSZ*32) + (size_t)px4*64 + cp;
    dst[0]  = (unsigned)f2h(a.x) | ((unsigned)f2h(b.x) << 16);
    dst[16] = (unsigned)f2h(a.y) | ((unsigned)f2h(b.y) << 16);
    dst[32] = (unsigned)f2h(a.z) | ((unsigned)f2h(b.z) << 16);
    dst[48] = (unsigned)f2h(a.w) | ((unsigned)f2h(b.w) << 16);
}

// Block: 64 out-ch x (4*WR rows x 32 cols), 256 thr = 4 waves.
// WR=2: wave wv = rows 2wv,2wv+1, P=4 (2 rows x 2 col-halves).
// WR=1: wave wv = row wv, P=2 (2 col-halves).
// LDS: 2x input [(4WR+2)][34][32] f16 XOR-swz + 1x weights [9][4][64][8]
// (36864 B).  WR=2: 80384 B, WR=1: 62976 B -> 2 blocks/CU (8 waves).
template<int EPI, int WR>
__global__ __launch_bounds__(256, 2)
void conv_mfma_k(const unsigned short* __restrict__ seg0b,
                 const unsigned short* __restrict__ seg1b,
                 const unsigned short* __restrict__ seg2b,
                 int nkb, int nkb_stride, int grp_base,
                 const unsigned short* __restrict__ pw,
                 const unsigned short* __restrict__ zp,
                 const float* __restrict__ bias,
                 const unsigned short* e_hb,     // f16 interl. h_{t-1} (null @t=0)
                 const unsigned short* __restrict__ e_updb, // CAND: upd f16 interl.
                 float* out_f,                   // CAND: out[t] fp32 planar
                 unsigned short* out_b,          // MSG: aggb(t<3) GATES: rhb CAND: hb
                 unsigned short* out_b2)         // MSG: aggb3    GATES: updb
{
    constexpr int ROWS   = 4*WR;                 // tile rows
    constexpr int PP     = 2*WR;                 // px-frags per wave
    constexpr int POS    = (ROWS+2)*34;          // tile positions incl. halo
    constexpr int HSLOTS = (68 + 2*ROWS)*4;      // halo 16B granules (336/304)
    constexpr int HEXT   = HSLOTS - 256;         // second-slot threads (80/48)

    __shared__ unsigned short s_in0[POS*32];
    __shared__ unsigned short s_in1[POS*32];
    __shared__ unsigned short s_w[9*4*64*8];     // 36864 B

    const int tid  = threadIdx.x;
    const int lane = tid & 63;
    const int wv   = tid >> 6;                   // 0..3
    const int n16  = lane & 15;
    const int q    = lane >> 4;

    int grp, ts = 0;
    if (EPI == EPI_MSG) { ts = blockIdx.z; grp = 0; }
    else                { grp = blockIdx.z + grp_base; }

    const unsigned short* s0 = seg0b + (EPI==EPI_MSG ? (size_t)ts*CHW : 0);
    const unsigned short* s1 = seg1b + (EPI==EPI_MSG ? (size_t)ts*CHW : 0);
    unsigned short* ob = out_b;
    if (EPI == EPI_MSG) ob = (ts < 3) ? out_b + (size_t)ts*CHW : out_b2;

    const int x0p = blockIdx.x * 32;
    const int y0  = blockIdx.y * ROWS;

    // ---- halo descriptors: ring = (68+2*ROWS) pos x 4 granules.
    // Thread tid owns slot tid and (if tid < HEXT) slot tid+256.
    int hdst0 = 0, hdst1 = 0; size_t hsrc0 = 0, hsrc1 = 0;
    bool hval0 = false, hval1 = false;
    {
        auto hcalc = [&](int s, int& hdst, size_t& hsrc, bool& hval) {
            int hp = s >> 2, gs = s & 3;
            int row, col;
            if (hp < 34)      { row = 0;      col = hp; }
            else if (hp < 68) { row = ROWS+1; col = hp - 34; }
            else { int k = hp - 68; row = 1 + (k >> 1); col = (k & 1) * 33; }
            int pos = row*34 + col;
            int gy = y0 + row - 1, gx = x0p + col - 1;
            hdst = (pos << 5) + (gs << 3);
            int g = (gs ^ pos ^ (pos >> 2)) & 3;
            if ((unsigned)gy < (unsigned)HH && (unsigned)gx < (unsigned)WW) {
                hval = true;
                hsrc = ((size_t)(gy*WW + gx) << 5) + (size_t)(g << 3);
            }
        };
        hcalc(tid, hdst0, hsrc0, hval0);
        if (tid < HEXT) hcalc(tid + 256, hdst1, hsrc1, hval1);
    }

    auto srcof = [&](int kb) -> const unsigned short* {
        return ((kb < 2) ? s0 : (kb < 4) ? s1 : seg2b) + (size_t)(kb & 1)*HWSZ*32;
    };

    struct HV { uint4v a, b; };
    auto halo_load = [&](int kb, HV& h) {
        const unsigned short* src = srcof(kb);
        h.a = *(const uint4v*)(hval0 ? src + hsrc0 : zp);
        if (tid < HEXT) h.b = *(const uint4v*)(hval1 ? src + hsrc1 : zp);
    };
    auto halo_write = [&](unsigned short* bin, const HV& h) {
        *(uint4v*)&bin[hdst0] = h.a;
        if (tid < HEXT) *(uint4v*)&bin[hdst1] = h.b;
    };

    // interior: ROWS x 2 col-halves = 2*ROWS wave-chunks, 2*WR per wave
    // (full 64B granules, inverse-swizzled source, linear LDS dest).
    auto stage_in = [&](int kb, unsigned short* bin) {
        const unsigned short* src = srcof(kb);
#pragma unroll
        for (int j = 0; j < 2*WR; ++j) {
            const int c    = wv + 4*j;           // 0..2*ROWS-1
            const int row  = 1 + (c >> 1);       // 1..ROWS
            const int colh = c & 1;
            const int gy   = y0 + row - 1;       // in [0,199] always
            const int p0   = row*34 + 1 + colh*16;
            const int pl   = p0 + (lane >> 2);
            const int g    = ((lane & 3) ^ pl ^ (pl >> 2)) & 3;
            const int gx   = x0p + colh*16 + (lane >> 2);
            load_lds16(src + (((size_t)(gy*WW + gx)) << 5) + (g << 3),
                       &bin[(size_t)p0 << 5]);
        }
    };
    auto stage_w = [&](int kb) {
        const unsigned short* wsrc = pw + (size_t)(grp*nkb_stride + kb)*18432;
#pragma unroll
        for (int i = 0; i < 9; ++i) {
            const int u = wv + 4*i;              // 0..35 exactly
            load_lds16(wsrc + (size_t)u*512 + (size_t)lane*8, &s_w[(size_t)u*512]);
        }
    };

    f32x4 acc[4][PP];
#pragma unroll
    for (int cf=0; cf<4; ++cf)
#pragma unroll
        for (int p=0; p<PP; ++p) acc[cf][p] = (f32x4){0.f,0.f,0.f,0.f};

    auto compute = [&](const unsigned short* sin) {
#pragma unroll
        for (int ky = 0; ky < 3; ++ky) {
#pragma unroll
            for (int kx = 0; kx < 3; ++kx) {
                const int sh = ky*3 + kx;
                f16x8 aw[4];
#pragma unroll
                for (int cf = 0; cf < 4; ++cf)
                    aw[cf] = *(const f16x8*)&s_w[((sh*4 + cf)*64 + lane)*8];
#pragma unroll
                for (int p = 0; p < PP; ++p) {
                    const int rl = (WR == 2 ? 2*wv + (p >> 1) : wv) + ky;
                    const int cl = 16*(WR == 2 ? (p & 1) : p) + n16 + kx;
                    const int pos = rl*34 + cl;
                    const int sw = (q ^ pos ^ (pos >> 2)) & 3;
                    f16x8 bfr = *(const f16x8*)&sin[(pos << 5) + (sw << 3)];
#pragma unroll
                    for (int cf = 0; cf < 4; ++cf)
                        acc[cf][p] = __builtin_amdgcn_mfma_f32_16x16x32_f16(
                                         aw[cf], bfr, acc[cf][p], 0, 0, 0);
                }
            }
        }
    };

    HV h0, h1;
    stage_in(0, s_in0);          // prologue: kb=0 input + weights + halo
    stage_w(0);
    halo_load(0, h0);

    for (int kb = 0; kb < nkb; kb += 2) {      // nkb even (4 or 6)
        // ===== phase A: buf0 = kb
        halo_write(s_in0, h0);                 // waits h0 (vmcnt dep)
        __syncthreads();                       // kb in+w DMAs landed, halo visible
        halo_load(kb + 1, h1);
        stage_in(kb + 1, s_in1);               // flies across compute
        __builtin_amdgcn_sched_barrier(0);
        compute(s_in0);
        __syncthreads();                       // all waves done reading s_w(kb)
        stage_w(kb + 1);
        // ===== phase B: buf1 = kb+1
        halo_write(s_in1, h1);
        __syncthreads();                       // kb+1 in+w DMAs landed
        if (kb + 2 < nkb) {
            halo_load(kb + 2, h0);
            stage_in(kb + 2, s_in0);
            __builtin_amdgcn_sched_barrier(0);
        }
        compute(s_in1);
        __syncthreads();
        if (kb + 2 < nkb) stage_w(kb + 2);
    }

    // ---- epilogue. C/D: pixel = lane&15, co = (lane>>4)*4 + reg
#pragma unroll
    for (int cf = 0; cf < 4; ++cf) {
        const int half   = cf >> 1;                // 32-ch half within co64
        const int cobase = grp*64 + cf*16 + q*4;   // global co of reg 0
        const int cmod   = (cf & 1)*16 + q*4;      // co within 32-plane
#pragma unroll
        for (int p = 0; p < PP; ++p) {
            const int row = y0 + (WR == 2 ? 2*wv + (p >> 1) : wv);
            const int col = x0p + 16*(WR == 2 ? (p & 1) : p) + n16;
            if (row >= HH) continue;
            const long pix = (long)row*WW + col;
            const size_t iidx = (((size_t)half*HWSZ + pix) << 5) + cmod;
            float v[4];
#pragma unroll
            for (int r = 0; r < 4; ++r) v[r] = acc[cf][p][r] + bias[cobase + r];

            if (EPI == EPI_MSG) {
                ushort4v xv = *(const ushort4v*)&s0[iidx];
                ushort4v s;
#pragma unroll
                for (int r = 0; r < 4; ++r)
                    s[r] = f2h(0.5f*(h2f(xv[r]) + v[r]));
                *(ushort4v*)&ob[iidx] = s;
            } else if (EPI == EPI_GATES) {
                if (grp == 0) {  // reset block -> rh = sigmoid * h
                    ushort4v hv = e_hb ? *(const ushort4v*)&e_hb[iidx]
                                       : (ushort4v){0,0,0,0};
                    ushort4v s;
#pragma unroll
                    for (int r = 0; r < 4; ++r) {
                        float g = 1.f/(1.f + __expf(-v[r]));
                        s[r] = f2h(g * h2f(hv[r]));
                    }
                    *(ushort4v*)&out_b[iidx] = s;
                } else {         // update block -> updb
                    ushort4v s;
#pragma unroll
                    for (int r = 0; r < 4; ++r)
                        s[r] = f2h(1.f/(1.f + __expf(-v[r])));
                    *(ushort4v*)&out_b2[iidx] = s;
                }
            } else {             // CAND: h_next -> out fp32 planar + hb f16
                ushort4v uv = *(const ushort4v*)&e_updb[iidx];
                ushort4v hv = e_hb ? *(const ushort4v*)&e_hb[iidx]
                                   : (ushort4v){0,0,0,0};
                ushort4v s;
#pragma unroll
                for (int r = 0; r < 4; ++r) {
                    float cnm = tanhf(v[r]);
                    float u   = h2f(uv[r]);
                    float hn  = (1.f - u)*h2f(hv[r]) + u*cnm;
                    out_f[(long)(cobase+r)*HWSZ + pix] = hn;
                    s[r] = f2h(hn);
                }
                *(ushort4v*)&out_b[iidx] = s;
            }
        }
    }
}

// ws (u16 units): xb0_all 4C | aggb3 C | rhb C | updb C | hb C | pw 405504
//   | zp 128  = 72.9 MB.   d_out aliases: xb1_all = out[0..1] (dead until
//   step 0 writes out[0]), aggb[0..2] = out[2..3].
extern "C" void kernel_launch(void* const* d_in, const int* in_sizes, int n_in,
                              void* d_out, int out_size, void* d_ws, size_t ws_size,
                              hipStream_t stream)
{
    const float* x       = (const float*)d_in[0];
    const float* msg_w   = (const float*)d_in[1];
    const float* msg_b   = (const float*)d_in[2];
    const float* gates_w = (const float*)d_in[3];
    const float* gates_b = (const float*)d_in[4];
    const float* can_w   = (const float*)d_in[5];
    const float* can_b   = (const float*)d_in[6];
    float* out = (float*)d_out;

    unsigned short* W       = (unsigned short*)d_ws;
    unsigned short* xb0_all = W;                  // [4][2][HWSZ][32]
    unsigned short* aggb3   = W + 4*CHW;
    unsigned short* rhb     = W + 5*CHW;
    unsigned short* updb    = W + 6*CHW;
    unsigned short* hb      = W + 7*CHW;
    unsigned short* pw      = W + 8*CHW;          // 405504 u16
    unsigned short* pw_msg  = pw;                 // cf4 msg   (1x4)
    unsigned short* pw_gat  = pw + 73728;         // cf4 gates (2x6)
    unsigned short* pw_can  = pw + 294912;        // cf4 cand  (1x6)
    unsigned short* zp      = pw + 405504;        // 128 u16 zero page

    unsigned short* outU16   = (unsigned short*)d_out;
    unsigned short* xb1_all  = outU16;            // 4*CHW u16 = out[0..1]
    unsigned short* aggbase  = outU16 + 4*CHW;    // aggb[0..2] = out[2..3]

    prepack_k<<<dim3(1585), dim3(256), 0, stream>>>(msg_w, gates_w, can_w, pw, zp);
    convert_all_k<<<dim3(17600), dim3(256), 0, stream>>>(x, xb0_all, xb1_all);

    // msg for all 4 t in one dispatch: Cin=[x0|x1], Cout=64 -> aggb[t].
    // WR=2: 1100 blocks (2/CU healthy).
    conv_mfma_k<EPI_MSG,2><<<dim3(11,25,4), dim3(256), 0, stream>>>(
        xb0_all, xb1_all, nullptr, 4, 4, 0, pw_msg, zp, msg_b,
        nullptr, nullptr, nullptr, aggbase, aggb3);

    for (int t = 0; t < 4; ++t) {
        const unsigned short* xt  = xb0_all + (size_t)t*CHW;
        const unsigned short* agt = (t < 3) ? aggbase + (size_t)t*CHW : aggb3;
        const unsigned short* hprev = t ? hb : nullptr;

        if (t == 0) {
            // t=0: h==0 -> reset*h==0 and CAND(nkb=4) never reads rhb;
            // update half only (grp_base=1). WR=1 -> 550 blocks, 8 waves/CU.
            conv_mfma_k<EPI_GATES,1><<<dim3(11,50,1), dim3(256), 0, stream>>>(
                xt, agt, nullptr, 4, 6, 1, pw_gat, zp, gates_b,
                nullptr, nullptr, nullptr, rhb, updb);
        } else {
            // gates: Cin=[x|agg|h], Cout=128; z=0 reset / z=1 update.
            // WR=2 -> 550 blocks.
            conv_mfma_k<EPI_GATES,2><<<dim3(11,25,2), dim3(256), 0, stream>>>(
                xt, agt, hb, 6, 6, 0, pw_gat, zp, gates_b,
                hprev, nullptr, nullptr, rhb, updb);
        }
        // cand: Cin=[x|agg|rh], Cout=64 -> out[t] fp32 + hb f16.
        // WR=1 -> 550 blocks, 8 waves/CU (fixes the 275-block hole).
        conv_mfma_k<EPI_CAND,1><<<dim3(11,50,1), dim3(256), 0, stream>>>(
            xt, agt, rhb, t ? 6 : 4, 6, 0, pw_can, zp, can_b,
            hprev, updb, out + (size_t)t*CHW, hb, nullptr);
    }
}

// Round 11
// 373.905 us; speedup vs baseline: 2.3651x; 1.0881x over previous
//
#include <hip/hip_runtime.h>
#include <math.h>
#include <string.h>

// V2VNetFusion on MI355X, round 15: cf4 + pipeline + 4 waves/SIMD.
// r14 (406us, best): WR=1 on CAND/GATES-t0 paid. Profile shows MSG
// pinned at 84-90us across EVERY config tried; the never-tested matrix
// cell is cf4+pipeline+4waves/SIMD (r0 had 4w/SIMD but cf2+no-pipe;
// r9/r14 have cf4+pipe but 2w/SIMD). Cycle model: ~6.9K LDS-cy/kb/CU
// vs ~24K wall-cy -> LDS pipe idles ~70% on ds_read->MFMA latency that
// 2 waves/SIMD can't hide. This round: 512-thread blocks, 8 waves,
// wave = 1 row x 32 cols (P=2), CF=4, same 8x32 tile, same 80384B LDS
// -> 2 blocks/CU = 16 waves/CU = 4 waves/SIMD. Same grids, same r14
// pipeline skeleton, uniform kernel. acc 64->32 VGPR; lb(512,4).
#define HH 200
#define WW 352
#define HWSZ (HH*WW)          // 70400
#define CHW (64L*HWSZ)        // one (64,H,W) tensor, elems

enum { EPI_MSG=0, EPI_GATES=1, EPI_CAND=2 };

typedef __attribute__((ext_vector_type(8))) _Float16 f16x8;
typedef __attribute__((ext_vector_type(4))) float f32x4;
typedef __attribute__((ext_vector_type(4))) unsigned int uint4v;
typedef __attribute__((ext_vector_type(4))) unsigned short ushort4v;

__device__ __forceinline__ unsigned short f2h(float f) {
    _Float16 h = (_Float16)f;                    // v_cvt_f16_f32 (RTE)
    return __builtin_bit_cast(unsigned short, h);
}
__device__ __forceinline__ float h2f(unsigned short u) {
    return (float)__builtin_bit_cast(_Float16, u);
}

// global->LDS DMA, 16B per lane. LDS dest = wave-uniform base + lane*16.
__device__ __forceinline__ void load_lds16(const unsigned short* g,
                                           unsigned short* l) {
    __builtin_amdgcn_global_load_lds(
        (const __attribute__((address_space(1))) unsigned int*)g,
        (__attribute__((address_space(3))) unsigned int*)l, 16, 0, 0);
}

// Prepack conv weights to f16, LDS-ready lane-major layout, CF=4:
// chunk(cogrp64,kb) = [sh(9)][cf(4)][lane(64)][8ch] = 18432 f16.
// lane = q*16+n16 -> co = cogrp*64 + cf*16+n16, ch = q*8+j.
// msg: 1x4, gates: 2x6, cand: 1x6 chunks. Tail threads zero the 256B
// zero-page (reg source for OOB halo).
__global__ void prepack_k(const float* __restrict__ mw,
                          const float* __restrict__ gw,
                          const float* __restrict__ cw,
                          unsigned short* __restrict__ pw,
                          unsigned short* __restrict__ zp)
{
    const int MSG_I = 4*18432;        // 73728
    const int GAT_I = 12*18432;       // 221184
    const int CAN_I = 6*18432;        // 110592
    const int TOTAL = MSG_I + GAT_I + CAN_I;   // 405504
    int idx = blockIdx.x*256 + threadIdx.x;
    if (idx >= TOTAL) {
        int r = idx - TOTAL;
        if (r < 128) zp[r] = 0;
        return;
    }
    const float* w; int cin, nkb, rel; unsigned short* base;
    if (idx < MSG_I)              { w=mw; cin=128; nkb=4; rel=idx;              base=pw; }
    else if (idx < MSG_I+GAT_I)   { w=gw; cin=192; nkb=6; rel=idx-MSG_I;        base=pw+73728; }
    else                          { w=cw; cin=192; nkb=6; rel=idx-MSG_I-GAT_I;  base=pw+294912; }
    int chunk = rel / 18432, r = rel - chunk*18432;
    int j = r & 7, lane = (r >> 3) & 63, cfsh = r >> 9;   // cfsh 0..35
    int cf = cfsh & 3, sh = cfsh >> 2;
    int q = lane >> 4, n16 = lane & 15;
    int co_l = cf*16 + n16, ch = q*8 + j;
    int cogrp = chunk / nkb, kb = chunk - cogrp*nkb;
    float f = w[(((long)(cogrp*64 + co_l))*cin + kb*32 + ch)*9 + sh];
    base[(size_t)chunk*18432 + r] = f2h(f);
}

// Convert x (2 agents x 4 t) fp32 planar -> f16 interleaved [t][half][pix][32].
__global__ void convert_all_k(const float* __restrict__ x,
                              unsigned short* __restrict__ xb0_all,
                              unsigned short* __restrict__ xb1_all)
{
    int idx = blockIdx.x*256 + threadIdx.x;      // 4,505,600 total
    int cp   = idx & 15;
    int rest = idx >> 4;
    int px4  = rest % 17600;
    int r2   = rest / 17600;                      // 0..15
    int hb = r2 & 1, ag = (r2 >> 1) & 1, t = r2 >> 2;
    const float* src = x + ((size_t)(ag*4 + t))*CHW
                         + (size_t)(hb*32 + 2*cp)*HWSZ + (size_t)px4*4;
    float4 a = *(const float4*)src;
    float4 b = *(const float4*)(src + HWSZ);
    unsigned int* dst = (unsigned int*)((ag ? xb1_all : xb0_all)
                        + (size_t)t*CHW + (size_t)hb*HWSZ*32) + (size_t)px4*64 + cp;
    dst[0]  = (unsigned)f2h(a.x) | ((unsigned)f2h(b.x) << 16);
    dst[16] = (unsigned)f2h(a.y) | ((unsigned)f2h(b.y) << 16);
    dst[32] = (unsigned)f2h(a.z) | ((unsigned)f2h(b.z) << 16);
    dst[48] = (unsigned)f2h(a.w) | ((unsigned)f2h(b.w) << 16);
}

// Block: 64 out-ch x (8 rows x 32 cols), 512 thr = 8 waves; wave wv =
// row wv (P=2 col-halves), CF=4.  LDS: 2x input [10][34][32] f16 XOR-swz
// (21760 B) + 1x weights [9][4][64][8] (36864 B) = 80384 B
// -> 2 blocks/CU = 16 waves/CU = 4 waves/SIMD.
template<int EPI>
__global__ __launch_bounds__(512, 4)
void conv_mfma_k(const unsigned short* __restrict__ seg0b,
                 const unsigned short* __restrict__ seg1b,
                 const unsigned short* __restrict__ seg2b,
                 int nkb, int nkb_stride, int grp_base,
                 const unsigned short* __restrict__ pw,
                 const unsigned short* __restrict__ zp,
                 const float* __restrict__ bias,
                 const unsigned short* e_hb,     // f16 interl. h_{t-1} (null @t=0)
                 const unsigned short* __restrict__ e_updb, // CAND: upd f16 interl.
                 float* out_f,                   // CAND: out[t] fp32 planar
                 unsigned short* out_b,          // MSG: aggb(t<3) GATES: rhb CAND: hb
                 unsigned short* out_b2)         // MSG: aggb3    GATES: updb
{
    constexpr int ROWS   = 8;                    // tile rows
    constexpr int HSLOTS = (68 + 2*ROWS)*4;      // 336 halo 16B granules

    __shared__ unsigned short s_in0[(ROWS+2)*34*32];   // 21760 B
    __shared__ unsigned short s_in1[(ROWS+2)*34*32];
    __shared__ unsigned short s_w[9*4*64*8];           // 36864 B

    const int tid  = threadIdx.x;
    const int lane = tid & 63;
    const int wv   = tid >> 6;                   // 0..7
    const int n16  = lane & 15;
    const int q    = lane >> 4;

    int grp, ts = 0;
    if (EPI == EPI_MSG) { ts = blockIdx.z; grp = 0; }
    else                { grp = blockIdx.z + grp_base; }

    const unsigned short* s0 = seg0b + (EPI==EPI_MSG ? (size_t)ts*CHW : 0);
    const unsigned short* s1 = seg1b + (EPI==EPI_MSG ? (size_t)ts*CHW : 0);
    unsigned short* ob = out_b;
    if (EPI == EPI_MSG) ob = (ts < 3) ? out_b + (size_t)ts*CHW : out_b2;

    const int x0p = blockIdx.x * 32;
    const int y0  = blockIdx.y * ROWS;

    // ---- halo descriptor: ring = 84 pos x 4 granules = 336 slots;
    // thread tid (<336) owns one slot.
    int hdst = 0; size_t hsrc = 0; bool hval = false;
    const bool hact = (tid < HSLOTS);
    if (hact) {
        int hp = tid >> 2, gs = tid & 3;
        int row, col;
        if (hp < 34)      { row = 0;      col = hp; }
        else if (hp < 68) { row = ROWS+1; col = hp - 34; }
        else { int k = hp - 68; row = 1 + (k >> 1); col = (k & 1) * 33; }
        int pos = row*34 + col;
        int gy = y0 + row - 1, gx = x0p + col - 1;
        hdst = (pos << 5) + (gs << 3);
        int g = (gs ^ pos ^ (pos >> 2)) & 3;
        if ((unsigned)gy < (unsigned)HH && (unsigned)gx < (unsigned)WW) {
            hval = true;
            hsrc = ((size_t)(gy*WW + gx) << 5) + (size_t)(g << 3);
        }
    }

    auto srcof = [&](int kb) -> const unsigned short* {
        return ((kb < 2) ? s0 : (kb < 4) ? s1 : seg2b) + (size_t)(kb & 1)*HWSZ*32;
    };

    auto halo_load = [&](int kb, uint4v& h) {
        const unsigned short* src = srcof(kb);
        if (hact) h = *(const uint4v*)(hval ? src + hsrc : zp);
    };
    auto halo_write = [&](unsigned short* bin, const uint4v& h) {
        if (hact) *(uint4v*)&bin[hdst] = h;
    };

    // interior: 8 rows x 2 col-halves = 16 wave-chunks, 2 per wave
    // (full 64B granules, inverse-swizzled source, linear LDS dest).
    auto stage_in = [&](int kb, unsigned short* bin) {
        const unsigned short* src = srcof(kb);
#pragma unroll
        for (int j = 0; j < 2; ++j) {
            const int c    = wv + 8*j;           // 0..15
            const int row  = 1 + (c >> 1);       // 1..8
            const int colh = c & 1;
            const int gy   = y0 + row - 1;       // in [0,199] always
            const int p0   = row*34 + 1 + colh*16;
            const int pl   = p0 + (lane >> 2);
            const int g    = ((lane & 3) ^ pl ^ (pl >> 2)) & 3;
            const int gx   = x0p + colh*16 + (lane >> 2);
            load_lds16(src + (((size_t)(gy*WW + gx)) << 5) + (g << 3),
                       &bin[(size_t)p0 << 5]);
        }
    };
    auto stage_w = [&](int kb) {
        const unsigned short* wsrc = pw + (size_t)(grp*nkb_stride + kb)*18432;
#pragma unroll
        for (int i = 0; i < 5; ++i) {
            const int u = wv + 8*i;              // 0..39; skip >=36
            if (u < 36)
                load_lds16(wsrc + (size_t)u*512 + (size_t)lane*8, &s_w[(size_t)u*512]);
        }
    };

    f32x4 acc[4][2];
#pragma unroll
    for (int cf=0; cf<4; ++cf)
#pragma unroll
        for (int p=0; p<2; ++p) acc[cf][p] = (f32x4){0.f,0.f,0.f,0.f};

    auto compute = [&](const unsigned short* sin) {
#pragma unroll
        for (int ky = 0; ky < 3; ++ky) {
#pragma unroll
            for (int kx = 0; kx < 3; ++kx) {
                const int sh = ky*3 + kx;
                f16x8 aw[4];
#pragma unroll
                for (int cf = 0; cf < 4; ++cf)
                    aw[cf] = *(const f16x8*)&s_w[((sh*4 + cf)*64 + lane)*8];
#pragma unroll
                for (int p = 0; p < 2; ++p) {
                    const int rl = wv + ky;
                    const int cl = 16*p + n16 + kx;
                    const int pos = rl*34 + cl;
                    const int sw = (q ^ pos ^ (pos >> 2)) & 3;
                    f16x8 bfr = *(const f16x8*)&sin[(pos << 5) + (sw << 3)];
#pragma unroll
                    for (int cf = 0; cf < 4; ++cf)
                        acc[cf][p] = __builtin_amdgcn_mfma_f32_16x16x32_f16(
                                         aw[cf], bfr, acc[cf][p], 0, 0, 0);
                }
            }
        }
    };

    uint4v h0, h1;
    stage_in(0, s_in0);          // prologue: kb=0 input + weights + halo
    stage_w(0);
    halo_load(0, h0);

    for (int kb = 0; kb < nkb; kb += 2) {      // nkb even (4 or 6)
        // ===== phase A: buf0 = kb
        halo_write(s_in0, h0);                 // waits h0 (vmcnt dep)
        __syncthreads();                       // kb in+w DMAs landed, halo visible
        halo_load(kb + 1, h1);
        stage_in(kb + 1, s_in1);               // flies across compute
        __builtin_amdgcn_sched_barrier(0);
        compute(s_in0);
        __syncthreads();                       // all waves done reading s_w(kb)
        stage_w(kb + 1);
        // ===== phase B: buf1 = kb+1
        halo_write(s_in1, h1);
        __syncthreads();                       // kb+1 in+w DMAs landed
        if (kb + 2 < nkb) {
            halo_load(kb + 2, h0);
            stage_in(kb + 2, s_in0);
            __builtin_amdgcn_sched_barrier(0);
        }
        compute(s_in1);
        __syncthreads();
        if (kb + 2 < nkb) stage_w(kb + 2);
    }

    // ---- epilogue. C/D: pixel = lane&15, co = (lane>>4)*4 + reg
#pragma unroll
    for (int cf = 0; cf < 4; ++cf) {
        const int half   = cf >> 1;                // 32-ch half within co64
        const int cobase = grp*64 + cf*16 + q*4;   // global co of reg 0
        const int cmod   = (cf & 1)*16 + q*4;      // co within 32-plane
#pragma unroll
        for (int p = 0; p < 2; ++p) {
            const int row = y0 + wv;               // always < 200
            const int col = x0p + 16*p + n16;
            const long pix = (long)row*WW + col;
            const size_t iidx = (((size_t)half*HWSZ + pix) << 5) + cmod;
            float v[4];
#pragma unroll
            for (int r = 0; r < 4; ++r) v[r] = acc[cf][p][r] + bias[cobase + r];

            if (EPI == EPI_MSG) {
                ushort4v xv = *(const ushort4v*)&s0[iidx];
                ushort4v s;
#pragma unroll
                for (int r = 0; r < 4; ++r)
                    s[r] = f2h(0.5f*(h2f(xv[r]) + v[r]));
                *(ushort4v*)&ob[iidx] = s;
            } else if (EPI == EPI_GATES) {
                if (grp == 0) {  // reset block -> rh = sigmoid * h
                    ushort4v hv = e_hb ? *(const ushort4v*)&e_hb[iidx]
                                       : (ushort4v){0,0,0,0};
                    ushort4v s;
#pragma unroll
                    for (int r = 0; r < 4; ++r) {
                        float g = 1.f/(1.f + __expf(-v[r]));
                        s[r] = f2h(g * h2f(hv[r]));
                    }
                    *(ushort4v*)&out_b[iidx] = s;
                } else {         // update block -> updb
                    ushort4v s;
#pragma unroll
                    for (int r = 0; r < 4; ++r)
                        s[r] = f2h(1.f/(1.f + __expf(-v[r])));
                    *(ushort4v*)&out_b2[iidx] = s;
                }
            } else {             // CAND: h_next -> out fp32 planar + hb f16
                ushort4v uv = *(const ushort4v*)&e_updb[iidx];
                ushort4v hv = e_hb ? *(const ushort4v*)&e_hb[iidx]
                                   : (ushort4v){0,0,0,0};
                ushort4v s;
#pragma unroll
                for (int r = 0; r < 4; ++r) {
                    float cnm = tanhf(v[r]);
                    float u   = h2f(uv[r]);
                    float hn  = (1.f - u)*h2f(hv[r]) + u*cnm;
                    out_f[(long)(cobase+r)*HWSZ + pix] = hn;
                    s[r] = f2h(hn);
                }
                *(ushort4v*)&out_b[iidx] = s;
            }
        }
    }
}

// ws (u16 units): xb0_all 4C | aggb3 C | rhb C | updb C | hb C | pw 405504
//   | zp 128  = 72.9 MB.   d_out aliases: xb1_all = out[0..1] (dead until
//   step 0 writes out[0]), aggb[0..2] = out[2..3].
extern "C" void kernel_launch(void* const* d_in, const int* in_sizes, int n_in,
                              void* d_out, int out_size, void* d_ws, size_t ws_size,
                              hipStream_t stream)
{
    const float* x       = (const float*)d_in[0];
    const float* msg_w   = (const float*)d_in[1];
    const float* msg_b   = (const float*)d_in[2];
    const float* gates_w = (const float*)d_in[3];
    const float* gates_b = (const float*)d_in[4];
    const float* can_w   = (const float*)d_in[5];
    const float* can_b   = (const float*)d_in[6];
    float* out = (float*)d_out;

    unsigned short* W       = (unsigned short*)d_ws;
    unsigned short* xb0_all = W;                  // [4][2][HWSZ][32]
    unsigned short* aggb3   = W + 4*CHW;
    unsigned short* rhb     = W + 5*CHW;
    unsigned short* updb    = W + 6*CHW;
    unsigned short* hb      = W + 7*CHW;
    unsigned short* pw      = W + 8*CHW;          // 405504 u16
    unsigned short* pw_msg  = pw;                 // cf4 msg   (1x4)
    unsigned short* pw_gat  = pw + 73728;         // cf4 gates (2x6)
    unsigned short* pw_can  = pw + 294912;        // cf4 cand  (1x6)
    unsigned short* zp      = pw + 405504;        // 128 u16 zero page

    unsigned short* outU16   = (unsigned short*)d_out;
    unsigned short* xb1_all  = outU16;            // 4*CHW u16 = out[0..1]
    unsigned short* aggbase  = outU16 + 4*CHW;    // aggb[0..2] = out[2..3]

    prepack_k<<<dim3(1585), dim3(256), 0, stream>>>(msg_w, gates_w, can_w, pw, zp);
    convert_all_k<<<dim3(17600), dim3(256), 0, stream>>>(x, xb0_all, xb1_all);

    // msg for all 4 t in one dispatch: Cin=[x0|x1], Cout=64 -> aggb[t].
    // 1100 blocks, 2/CU, 16 waves/CU.
    conv_mfma_k<EPI_MSG><<<dim3(11,25,4), dim3(512), 0, stream>>>(
        xb0_all, xb1_all, nullptr, 4, 4, 0, pw_msg, zp, msg_b,
        nullptr, nullptr, nullptr, aggbase, aggb3);

    for (int t = 0; t < 4; ++t) {
        const unsigned short* xt  = xb0_all + (size_t)t*CHW;
        const unsigned short* agt = (t < 3) ? aggbase + (size_t)t*CHW : aggb3;
        const unsigned short* hprev = t ? hb : nullptr;

        if (t == 0) {
            // t=0: h==0 -> reset*h==0 and CAND(nkb=4) never reads rhb;
            // update half only (grp_base=1). 275 blocks.
            conv_mfma_k<EPI_GATES><<<dim3(11,25,1), dim3(512), 0, stream>>>(
                xt, agt, nullptr, 4, 6, 1, pw_gat, zp, gates_b,
                nullptr, nullptr, nullptr, rhb, updb);
        } else {
            // gates: Cin=[x|agg|h], Cout=128; z=0 reset / z=1 update.
            // 550 blocks.
            conv_mfma_k<EPI_GATES><<<dim3(11,25,2), dim3(512), 0, stream>>>(
                xt, agt, hb, 6, 6, 0, pw_gat, zp, gates_b,
                hprev, nullptr, nullptr, rhb, updb);
        }
        // cand: Cin=[x|agg|rh], Cout=64 -> out[t] fp32 + hb f16. 275 blocks.
        conv_mfma_k<EPI_CAND><<<dim3(11,25,1), dim3(512), 0, stream>>>(
            xt, agt, rhb, t ? 6 : 4, 6, 0, pw_can, zp, can_b,
            hprev, updb, out + (size_t)t*CHW, hb, nullptr);
    }
}

// Round 12
// 373.558 us; speedup vs baseline: 2.3674x; 1.0009x over previous
//
#include <hip/hip_runtime.h>
#include <math.h>
#include <string.h>

// V2VNetFusion on MI355X, round 16: r15 (373.9us, best) + TW=16 tiles
// for the four 275-block dispatches + setprio.
// r15 confirmed waves/SIMD is THE lever (4w/SIMD on MSG/GATES paid +33us).
// Remaining weak cells: CAND x4 + GATES-t0 at 275 blocks = 1.07 blk/CU.
// TW template: tile = 8 rows x TW cols.
//   TW=32: r15 verbatim (wave = 1 row x 32 col, P=2, LDS 80384).
//          MSG (1100 blk), GATES t>0 (550 blk). 2 blk/CU, 4 w/SIMD.
//   TW=16: wave = 1 row x 16 col (P=1), LDS = 2x11520+36864 = 59904
//          -> grid (22,25) = 550 blk, 2 blk/CU, 4 w/SIMD.
//          CAND all t, GATES t0.
// Plus T5: s_setprio(1) around the MFMA cluster (phase-split schedule:
// co-resident block stages while this one computes -> role diversity).
#define HH 200
#define WW 352
#define HWSZ (HH*WW)          // 70400
#define CHW (64L*HWSZ)        // one (64,H,W) tensor, elems

enum { EPI_MSG=0, EPI_GATES=1, EPI_CAND=2 };

typedef __attribute__((ext_vector_type(8))) _Float16 f16x8;
typedef __attribute__((ext_vector_type(4))) float f32x4;
typedef __attribute__((ext_vector_type(4))) unsigned int uint4v;
typedef __attribute__((ext_vector_type(4))) unsigned short ushort4v;

__device__ __forceinline__ unsigned short f2h(float f) {
    _Float16 h = (_Float16)f;                    // v_cvt_f16_f32 (RTE)
    return __builtin_bit_cast(unsigned short, h);
}
__device__ __forceinline__ float h2f(unsigned short u) {
    return (float)__builtin_bit_cast(_Float16, u);
}

// global->LDS DMA, 16B per lane. LDS dest = wave-uniform base + lane*16.
__device__ __forceinline__ void load_lds16(const unsigned short* g,
                                           unsigned short* l) {
    __builtin_amdgcn_global_load_lds(
        (const __attribute__((address_space(1))) unsigned int*)g,
        (__attribute__((address_space(3))) unsigned int*)l, 16, 0, 0);
}

// Prepack conv weights to f16, LDS-ready lane-major layout, CF=4:
// chunk(cogrp64,kb) = [sh(9)][cf(4)][lane(64)][8ch] = 18432 f16.
// lane = q*16+n16 -> co = cogrp*64 + cf*16+n16, ch = q*8+j.
// msg: 1x4, gates: 2x6, cand: 1x6 chunks. Tail threads zero the 256B
// zero-page (reg source for OOB halo).
__global__ void prepack_k(const float* __restrict__ mw,
                          const float* __restrict__ gw,
                          const float* __restrict__ cw,
                          unsigned short* __restrict__ pw,
                          unsigned short* __restrict__ zp)
{
    const int MSG_I = 4*18432;        // 73728
    const int GAT_I = 12*18432;       // 221184
    const int CAN_I = 6*18432;        // 110592
    const int TOTAL = MSG_I + GAT_I + CAN_I;   // 405504
    int idx = blockIdx.x*256 + threadIdx.x;
    if (idx >= TOTAL) {
        int r = idx - TOTAL;
        if (r < 128) zp[r] = 0;
        return;
    }
    const float* w; int cin, nkb, rel; unsigned short* base;
    if (idx < MSG_I)              { w=mw; cin=128; nkb=4; rel=idx;              base=pw; }
    else if (idx < MSG_I+GAT_I)   { w=gw; cin=192; nkb=6; rel=idx-MSG_I;        base=pw+73728; }
    else                          { w=cw; cin=192; nkb=6; rel=idx-MSG_I-GAT_I;  base=pw+294912; }
    int chunk = rel / 18432, r = rel - chunk*18432;
    int j = r & 7, lane = (r >> 3) & 63, cfsh = r >> 9;   // cfsh 0..35
    int cf = cfsh & 3, sh = cfsh >> 2;
    int q = lane >> 4, n16 = lane & 15;
    int co_l = cf*16 + n16, ch = q*8 + j;
    int cogrp = chunk / nkb, kb = chunk - cogrp*nkb;
    float f = w[(((long)(cogrp*64 + co_l))*cin + kb*32 + ch)*9 + sh];
    base[(size_t)chunk*18432 + r] = f2h(f);
}

// Convert x (2 agents x 4 t) fp32 planar -> f16 interleaved [t][half][pix][32].
__global__ void convert_all_k(const float* __restrict__ x,
                              unsigned short* __restrict__ xb0_all,
                              unsigned short* __restrict__ xb1_all)
{
    int idx = blockIdx.x*256 + threadIdx.x;      // 4,505,600 total
    int cp   = idx & 15;
    int rest = idx >> 4;
    int px4  = rest % 17600;
    int r2   = rest / 17600;                      // 0..15
    int hb = r2 & 1, ag = (r2 >> 1) & 1, t = r2 >> 2;
    const float* src = x + ((size_t)(ag*4 + t))*CHW
                         + (size_t)(hb*32 + 2*cp)*HWSZ + (size_t)px4*4;
    float4 a = *(const float4*)src;
    float4 b = *(const float4*)(src + HWSZ);
    unsigned int* dst = (unsigned int*)((ag ? xb1_all : xb0_all)
                        + (size_t)t*CHW + (size_t)hb*HWSZ*32) + (size_t)px4*64 + cp;
    dst[0]  = (unsigned)f2h(a.x) | ((unsigned)f2h(b.x) << 16);
    dst[16] = (unsigned)f2h(a.y) | ((unsigned)f2h(b.y) << 16);
    dst[32] = (unsigned)f2h(a.z) | ((unsigned)f2h(b.z) << 16);
    dst[48] = (unsigned)f2h(a.w) | ((unsigned)f2h(b.w) << 16);
}

// Block: 64 out-ch x (8 rows x TW cols), 512 thr = 8 waves; wave wv =
// row wv (P = TW/16 col-halves), CF=4.
// LDS: 2x input [10][TW+2][32] f16 XOR-swz + 1x weights [9][4][64][8]
// (36864 B).  TW=32: 80384 B, TW=16: 59904 B -> 2 blocks/CU, 4 w/SIMD.
template<int EPI, int TW>
__global__ __launch_bounds__(512, 4)
void conv_mfma_k(const unsigned short* __restrict__ seg0b,
                 const unsigned short* __restrict__ seg1b,
                 const unsigned short* __restrict__ seg2b,
                 int nkb, int nkb_stride, int grp_base,
                 const unsigned short* __restrict__ pw,
                 const unsigned short* __restrict__ zp,
                 const float* __restrict__ bias,
                 const unsigned short* e_hb,     // f16 interl. h_{t-1} (null @t=0)
                 const unsigned short* __restrict__ e_updb, // CAND: upd f16 interl.
                 float* out_f,                   // CAND: out[t] fp32 planar
                 unsigned short* out_b,          // MSG: aggb(t<3) GATES: rhb CAND: hb
                 unsigned short* out_b2)         // MSG: aggb3    GATES: updb
{
    constexpr int ROWS   = 8;                    // tile rows
    constexpr int TC     = TW + 2;               // tile pitch (34 / 18)
    constexpr int PP     = TW / 16;              // px-frags per wave (2 / 1)
    constexpr int HSLOTS = (2*TC + 16)*4;        // halo granules (336 / 208)

    __shared__ unsigned short s_in0[(ROWS+2)*TC*32];
    __shared__ unsigned short s_in1[(ROWS+2)*TC*32];
    __shared__ unsigned short s_w[9*4*64*8];           // 36864 B

    const int tid  = threadIdx.x;
    const int lane = tid & 63;
    const int wv   = tid >> 6;                   // 0..7
    const int n16  = lane & 15;
    const int q    = lane >> 4;

    int grp, ts = 0;
    if (EPI == EPI_MSG) { ts = blockIdx.z; grp = 0; }
    else                { grp = blockIdx.z + grp_base; }

    const unsigned short* s0 = seg0b + (EPI==EPI_MSG ? (size_t)ts*CHW : 0);
    const unsigned short* s1 = seg1b + (EPI==EPI_MSG ? (size_t)ts*CHW : 0);
    unsigned short* ob = out_b;
    if (EPI == EPI_MSG) ob = (ts < 3) ? out_b + (size_t)ts*CHW : out_b2;

    const int x0p = blockIdx.x * TW;
    const int y0  = blockIdx.y * ROWS;

    // ---- halo descriptor: ring = (2*TC+16) pos x 4 granules; thread
    // tid (< HSLOTS) owns one slot.
    int hdst = 0; size_t hsrc = 0; bool hval = false;
    const bool hact = (tid < HSLOTS);
    if (hact) {
        int hp = tid >> 2, gs = tid & 3;
        int row, col;
        if (hp < TC)        { row = 0;      col = hp; }
        else if (hp < 2*TC) { row = ROWS+1; col = hp - TC; }
        else { int k = hp - 2*TC; row = 1 + (k >> 1); col = (k & 1)*(TC-1); }
        int pos = row*TC + col;
        int gy = y0 + row - 1, gx = x0p + col - 1;
        hdst = (pos << 5) + (gs << 3);
        int g = (gs ^ pos ^ (pos >> 2)) & 3;
        if ((unsigned)gy < (unsigned)HH && (unsigned)gx < (unsigned)WW) {
            hval = true;
            hsrc = ((size_t)(gy*WW + gx) << 5) + (size_t)(g << 3);
        }
    }

    auto srcof = [&](int kb) -> const unsigned short* {
        return ((kb < 2) ? s0 : (kb < 4) ? s1 : seg2b) + (size_t)(kb & 1)*HWSZ*32;
    };

    auto halo_load = [&](int kb, uint4v& h) {
        const unsigned short* src = srcof(kb);
        if (hact) h = *(const uint4v*)(hval ? src + hsrc : zp);
    };
    auto halo_write = [&](unsigned short* bin, const uint4v& h) {
        if (hact) *(uint4v*)&bin[hdst] = h;
    };

    // interior: 8 rows x PP col-halves = 8*PP wave-chunks, PP per wave
    // (full 64B granules, inverse-swizzled source, linear LDS dest).
    auto stage_in = [&](int kb, unsigned short* bin) {
        const unsigned short* src = srcof(kb);
#pragma unroll
        for (int j = 0; j < PP; ++j) {
            const int c    = wv + 8*j;           // 0..8*PP-1
            const int row  = (PP == 2) ? 1 + (c >> 1) : 1 + c;
            const int colh = (PP == 2) ? (c & 1) : 0;
            const int gy   = y0 + row - 1;       // in [0,199] always
            const int p0   = row*TC + 1 + colh*16;
            const int pl   = p0 + (lane >> 2);
            const int g    = ((lane & 3) ^ pl ^ (pl >> 2)) & 3;
            const int gx   = x0p + colh*16 + (lane >> 2);
            load_lds16(src + (((size_t)(gy*WW + gx)) << 5) + (g << 3),
                       &bin[(size_t)p0 << 5]);
        }
    };
    auto stage_w = [&](int kb) {
        const unsigned short* wsrc = pw + (size_t)(grp*nkb_stride + kb)*18432;
#pragma unroll
        for (int i = 0; i < 5; ++i) {
            const int u = wv + 8*i;              // 0..39; skip >=36
            if (u < 36)
                load_lds16(wsrc + (size_t)u*512 + (size_t)lane*8, &s_w[(size_t)u*512]);
        }
    };

    f32x4 acc[4][PP];
#pragma unroll
    for (int cf=0; cf<4; ++cf)
#pragma unroll
        for (int p=0; p<PP; ++p) acc[cf][p] = (f32x4){0.f,0.f,0.f,0.f};

    auto compute = [&](const unsigned short* sin) {
        __builtin_amdgcn_s_setprio(1);
#pragma unroll
        for (int ky = 0; ky < 3; ++ky) {
#pragma unroll
            for (int kx = 0; kx < 3; ++kx) {
                const int sh = ky*3 + kx;
                f16x8 aw[4];
#pragma unroll
                for (int cf = 0; cf < 4; ++cf)
                    aw[cf] = *(const f16x8*)&s_w[((sh*4 + cf)*64 + lane)*8];
#pragma unroll
                for (int p = 0; p < PP; ++p) {
                    const int rl = wv + ky;
                    const int cl = 16*p + n16 + kx;
                    const int pos = rl*TC + cl;
                    const int sw = (q ^ pos ^ (pos >> 2)) & 3;
                    f16x8 bfr = *(const f16x8*)&sin[(pos << 5) + (sw << 3)];
#pragma unroll
                    for (int cf = 0; cf < 4; ++cf)
                        acc[cf][p] = __builtin_amdgcn_mfma_f32_16x16x32_f16(
                                         aw[cf], bfr, acc[cf][p], 0, 0, 0);
                }
            }
        }
        __builtin_amdgcn_s_setprio(0);
    };

    uint4v h0, h1;
    stage_in(0, s_in0);          // prologue: kb=0 input + weights + halo
    stage_w(0);
    halo_load(0, h0);

    for (int kb = 0; kb < nkb; kb += 2) {      // nkb even (4 or 6)
        // ===== phase A: buf0 = kb
        halo_write(s_in0, h0);                 // waits h0 (vmcnt dep)
        __syncthreads();                       // kb in+w DMAs landed, halo visible
        halo_load(kb + 1, h1);
        stage_in(kb + 1, s_in1);               // flies across compute
        __builtin_amdgcn_sched_barrier(0);
        compute(s_in0);
        __syncthreads();                       // all waves done reading s_w(kb)
        stage_w(kb + 1);
        // ===== phase B: buf1 = kb+1
        halo_write(s_in1, h1);
        __syncthreads();                       // kb+1 in+w DMAs landed
        if (kb + 2 < nkb) {
            halo_load(kb + 2, h0);
            stage_in(kb + 2, s_in0);
            __builtin_amdgcn_sched_barrier(0);
        }
        compute(s_in1);
        __syncthreads();
        if (kb + 2 < nkb) stage_w(kb + 2);
    }

    // ---- epilogue. C/D: pixel = lane&15, co = (lane>>4)*4 + reg
#pragma unroll
    for (int cf = 0; cf < 4; ++cf) {
        const int half   = cf >> 1;                // 32-ch half within co64
        const int cobase = grp*64 + cf*16 + q*4;   // global co of reg 0
        const int cmod   = (cf & 1)*16 + q*4;      // co within 32-plane
#pragma unroll
        for (int p = 0; p < PP; ++p) {
            const int row = y0 + wv;               // always < 200
            const int col = x0p + 16*p + n16;
            const long pix = (long)row*WW + col;
            const size_t iidx = (((size_t)half*HWSZ + pix) << 5) + cmod;
            float v[4];
#pragma unroll
            for (int r = 0; r < 4; ++r) v[r] = acc[cf][p][r] + bias[cobase + r];

            if (EPI == EPI_MSG) {
                ushort4v xv = *(const ushort4v*)&s0[iidx];
                ushort4v s;
#pragma unroll
                for (int r = 0; r < 4; ++r)
                    s[r] = f2h(0.5f*(h2f(xv[r]) + v[r]));
                *(ushort4v*)&ob[iidx] = s;
            } else if (EPI == EPI_GATES) {
                if (grp == 0) {  // reset block -> rh = sigmoid * h
                    ushort4v hv = e_hb ? *(const ushort4v*)&e_hb[iidx]
                                       : (ushort4v){0,0,0,0};
                    ushort4v s;
#pragma unroll
                    for (int r = 0; r < 4; ++r) {
                        float g = 1.f/(1.f + __expf(-v[r]));
                        s[r] = f2h(g * h2f(hv[r]));
                    }
                    *(ushort4v*)&out_b[iidx] = s;
                } else {         // update block -> updb
                    ushort4v s;
#pragma unroll
                    for (int r = 0; r < 4; ++r)
                        s[r] = f2h(1.f/(1.f + __expf(-v[r])));
                    *(ushort4v*)&out_b2[iidx] = s;
                }
            } else {             // CAND: h_next -> out fp32 planar + hb f16
                ushort4v uv = *(const ushort4v*)&e_updb[iidx];
                ushort4v hv = e_hb ? *(const ushort4v*)&e_hb[iidx]
                                   : (ushort4v){0,0,0,0};
                ushort4v s;
#pragma unroll
                for (int r = 0; r < 4; ++r) {
                    float cnm = tanhf(v[r]);
                    float u   = h2f(uv[r]);
                    float hn  = (1.f - u)*h2f(hv[r]) + u*cnm;
                    out_f[(long)(cobase+r)*HWSZ + pix] = hn;
                    s[r] = f2h(hn);
                }
                *(ushort4v*)&out_b[iidx] = s;
            }
        }
    }
}

// ws (u16 units): xb0_all 4C | aggb3 C | rhb C | updb C | hb C | pw 405504
//   | zp 128  = 72.9 MB.   d_out aliases: xb1_all = out[0..1] (dead until
//   step 0 writes out[0]), aggb[0..2] = out[2..3].
extern "C" void kernel_launch(void* const* d_in, const int* in_sizes, int n_in,
                              void* d_out, int out_size, void* d_ws, size_t ws_size,
                              hipStream_t stream)
{
    const float* x       = (const float*)d_in[0];
    const float* msg_w   = (const float*)d_in[1];
    const float* msg_b   = (const float*)d_in[2];
    const float* gates_w = (const float*)d_in[3];
    const float* gates_b = (const float*)d_in[4];
    const float* can_w   = (const float*)d_in[5];
    const float* can_b   = (const float*)d_in[6];
    float* out = (float*)d_out;

    unsigned short* W       = (unsigned short*)d_ws;
    unsigned short* xb0_all = W;                  // [4][2][HWSZ][32]
    unsigned short* aggb3   = W + 4*CHW;
    unsigned short* rhb     = W + 5*CHW;
    unsigned short* updb    = W + 6*CHW;
    unsigned short* hb      = W + 7*CHW;
    unsigned short* pw      = W + 8*CHW;          // 405504 u16
    unsigned short* pw_msg  = pw;                 // cf4 msg   (1x4)
    unsigned short* pw_gat  = pw + 73728;         // cf4 gates (2x6)
    unsigned short* pw_can  = pw + 294912;        // cf4 cand  (1x6)
    unsigned short* zp      = pw + 405504;        // 128 u16 zero page

    unsigned short* outU16   = (unsigned short*)d_out;
    unsigned short* xb1_all  = outU16;            // 4*CHW u16 = out[0..1]
    unsigned short* aggbase  = outU16 + 4*CHW;    // aggb[0..2] = out[2..3]

    prepack_k<<<dim3(1585), dim3(256), 0, stream>>>(msg_w, gates_w, can_w, pw, zp);
    convert_all_k<<<dim3(17600), dim3(256), 0, stream>>>(x, xb0_all, xb1_all);

    // msg for all 4 t in one dispatch: Cin=[x0|x1], Cout=64 -> aggb[t].
    // TW=32: 1100 blocks, 2/CU, 4 waves/SIMD.
    conv_mfma_k<EPI_MSG,32><<<dim3(11,25,4), dim3(512), 0, stream>>>(
        xb0_all, xb1_all, nullptr, 4, 4, 0, pw_msg, zp, msg_b,
        nullptr, nullptr, nullptr, aggbase, aggb3);

    for (int t = 0; t < 4; ++t) {
        const unsigned short* xt  = xb0_all + (size_t)t*CHW;
        const unsigned short* agt = (t < 3) ? aggbase + (size_t)t*CHW : aggb3;
        const unsigned short* hprev = t ? hb : nullptr;

        if (t == 0) {
            // t=0: h==0 -> reset*h==0 and CAND(nkb=4) never reads rhb;
            // update half only (grp_base=1). TW=16 -> 550 blocks.
            conv_mfma_k<EPI_GATES,16><<<dim3(22,25,1), dim3(512), 0, stream>>>(
                xt, agt, nullptr, 4, 6, 1, pw_gat, zp, gates_b,
                nullptr, nullptr, nullptr, rhb, updb);
        } else {
            // gates: Cin=[x|agg|h], Cout=128; z=0 reset / z=1 update.
            // TW=32: 550 blocks.
            conv_mfma_k<EPI_GATES,32><<<dim3(11,25,2), dim3(512), 0, stream>>>(
                xt, agt, hb, 6, 6, 0, pw_gat, zp, gates_b,
                hprev, nullptr, nullptr, rhb, updb);
        }
        // cand: Cin=[x|agg|rh], Cout=64 -> out[t] fp32 + hb f16.
        // TW=16 -> 550 blocks, 2/CU, 4 waves/SIMD.
        conv_mfma_k<EPI_CAND,16><<<dim3(22,25,1), dim3(512), 0, stream>>>(
            xt, agt, rhb, t ? 6 : 4, 6, 0, pw_can, zp, can_b,
            hprev, updb, out + (size_t)t*CHW, hb, nullptr);
    }
}